// Round 3
// baseline (1004.332 us; speedup 1.0000x reference)
//
#include <hip/hip_runtime.h>
#include <hip/hip_bf16.h>

// Problem sizes (fixed)
#define N_   10000
#define E_   100000
#define B_   64
#define DIM_ 64
#define NF_  92
#define EF_  50
#define H_   128

typedef unsigned int u32;

__device__ __forceinline__ float sigm(float x) { return 1.f / (1.f + __expf(-x)); }
__device__ __forceinline__ float rdlane(float v, int l) {
  return __uint_as_float(__builtin_amdgcn_readlane(__float_as_uint(v), l));
}

// ---------------- lin0: out = relu(x @ lin0_w.T + b)  [N, DIM] ----------------
// Weights staged in LDS (93-pad -> 2-way bank aliasing, free).
__global__ __launch_bounds__(256) void k_lin0(const float* __restrict__ x,
                                              const float* __restrict__ w,
                                              const float* __restrict__ b,
                                              float* __restrict__ out) {
  __shared__ float xs[4][NF_];
  __shared__ float w_s[DIM_][93];
  int n0 = blockIdx.x << 2;
  int tid = threadIdx.x;
  for (int k = tid; k < 4 * NF_; k += 256) {
    int nl = k / NF_, f = k % NF_;
    xs[nl][f] = x[(size_t)(n0 + nl) * NF_ + f];
  }
  for (int g = tid; g < DIM_ * NF_; g += 256) {
    int d = g / NF_, f = g % NF_;
    w_s[d][f] = w[g];
  }
  __syncthreads();
  int nl = tid >> 6, d = tid & 63;
  float acc = b[d];
  for (int f = 0; f < NF_; ++f) acc += xs[nl][f] * w_s[d][f];
  out[(size_t)(n0 + nl) * DIM_ + d] = fmaxf(acc, 0.f);
}

// ---------------- he = relu(edge_attr @ nn1_w.T + b)  [E, H] ----------------
__global__ __launch_bounds__(256) void k_he(const float* __restrict__ ea,
                                            const float* __restrict__ w,
                                            const float* __restrict__ b,
                                            float* __restrict__ he) {
  __shared__ float wt[EF_][132];  // wt[f][h]
  __shared__ float es[32][52];    // es[e][f]
  int e0 = blockIdx.x * 32, t = threadIdx.x;
  for (int g = t; g < H_ * EF_; g += 256) {
    int h = g / EF_, f = g % EF_;
    wt[f][h] = w[g];
  }
  for (int g = t; g < 32 * EF_; g += 256) {
    int e = g / EF_, f = g % EF_;
    es[e][f] = ea[(size_t)(e0 + e) * EF_ + f];
  }
  __syncthreads();
  int h0 = (t & 31) << 2, eg = t >> 5;  // eg in [0,8): 4 edges each
  float acc[4][4];
#pragma unroll
  for (int j = 0; j < 4; ++j)
#pragma unroll
    for (int c = 0; c < 4; ++c) acc[j][c] = b[h0 + c];
  for (int f = 0; f < EF_; ++f) {
    float4 wv = *(const float4*)&wt[f][h0];
    const float* wp = (const float*)&wv;
#pragma unroll
    for (int j = 0; j < 4; ++j) {
      float ev = es[eg * 4 + j][f];
#pragma unroll
      for (int c = 0; c < 4; ++c) acc[j][c] = fmaf(ev, wp[c], acc[j][c]);
    }
  }
#pragma unroll
  for (int j = 0; j < 4; ++j) {
    float4 o;
    o.x = fmaxf(acc[j][0], 0.f); o.y = fmaxf(acc[j][1], 0.f);
    o.z = fmaxf(acc[j][2], 0.f); o.w = fmaxf(acc[j][3], 0.f);
    *(float4*)&he[(size_t)(e0 + eg * 4 + j) * H_ + h0] = o;
  }
}

// ------------- histograms: out-degree (int, by src), in-degree (float, by dst) --
__global__ __launch_bounds__(256) void k_hist(const int* __restrict__ ei,
                                              int* __restrict__ outcnt,
                                              float* __restrict__ degf) {
  int e = blockIdx.x * 256 + threadIdx.x;
  if (e < E_) {
    atomicAdd(&outcnt[ei[e]], 1);
    atomicAdd(&degf[ei[E_ + e]], 1.0f);
  }
}

// ------------- exclusive scan of outcnt -> estart[N+1], cursor ----------------
__global__ __launch_bounds__(1024) void k_scan(const int* __restrict__ outcnt,
                                               int* __restrict__ estart,
                                               int* __restrict__ cursor) {
  __shared__ int part[1024];
  int t = threadIdx.x;
  int base = t * 10;
  int c[10];
  int s = 0;
#pragma unroll
  for (int j = 0; j < 10; ++j) {
    int idx = base + j;
    c[j] = (idx < N_) ? outcnt[idx] : 0;
    s += c[j];
  }
  part[t] = s;
  __syncthreads();
  for (int off = 1; off < 1024; off <<= 1) {
    int v = (t >= off) ? part[t - off] : 0;
    __syncthreads();
    part[t] += v;
    __syncthreads();
  }
  int ex = (t > 0) ? part[t - 1] : 0;
#pragma unroll
  for (int j = 0; j < 10; ++j) {
    int idx = base + j;
    if (idx < N_) { estart[idx] = ex; cursor[idx] = ex; }
    ex += c[j];
  }
  if (t == 1023) estart[N_] = part[1023];
}

// ---------------- scatter: eorder grouped by src ----------------
__global__ __launch_bounds__(256) void k_scatter(const int* __restrict__ ei,
                                                 int* __restrict__ cursor,
                                                 int* __restrict__ eorder) {
  int e = blockIdx.x * 256 + threadIdx.x;
  if (e < E_) {
    int s = ei[e];
    int pos = atomicAdd(&cursor[s], 1);
    eorder[pos] = e;
  }
}

// ---------------- graph start offsets from sorted batch ----------------
__global__ __launch_bounds__(256) void k_gstart(const int* __restrict__ batch,
                                                int* __restrict__ gs) {
  int n = blockIdx.x * 256 + threadIdx.x;
  if (n >= N_) return;
  int b = batch[n];
  if (n == 0) {
    for (int bb = 0; bb <= b; ++bb) gs[bb] = 0;
  } else {
    int pb = batch[n - 1];
    if (pb != b)
      for (int bb = pb + 1; bb <= b; ++bb) gs[bb] = n;
  }
  if (n == N_ - 1) {
    for (int bb = b + 1; bb <= B_; ++bb) gs[bb] = N_;
  }
}

// ---------------- V-GEMM: V[n,h,o] = sum_i out[n,i]*nn2_w[(i*64+o)*128+h] -------
// Tile: 128 nodes x 128 cols; cols = 16 o x 8 h (so stores land in 256B runs).
// blockIdx.y = og*(CW/8)+hg: og in [0,4) o-group of 16; hg selects 8-h subtile
// within the current CW-wide h-chunk (chunk base = h_base).
// V4 float4 layout (chunk-local): [(n*H4Cbuf + h4)*64 + o]  -> k_edge reads 1KB
// contiguous per wave. A staged in LDS with 2-shift swizzle (<=2-way).
__global__ __launch_bounds__(256) void k_vgemm(const float* __restrict__ outv,
                                               const float* __restrict__ nn2w,
                                               float* __restrict__ V4,
                                               int h_base, int H4Cbuf, int lwHg) {
  __shared__ float a_s[128][64];  // [node][i swizzled]
  __shared__ float b_s[64][128];  // [i][col]
  int n0 = blockIdx.x << 7;
  int og = blockIdx.y >> lwHg;
  int hg = blockIdx.y & ((1 << lwHg) - 1);
  int o0 = og << 4;
  int h0 = h_base + (hg << 3);
  int t = threadIdx.x;
#pragma unroll
  for (int k = 0; k < 8; ++k) {
    int idx = t + (k << 8);          // 0..2047
    int nl = idx >> 4, i0 = (idx & 15) << 2;
    float4 v = make_float4(0.f, 0.f, 0.f, 0.f);
    int n = n0 + nl;
    if (n < N_) v = *(const float4*)&outv[(size_t)n * 64 + i0];
    int sh = 2 * nl;
    int c0 = (i0 + sh) & 63;
    a_s[nl][c0] = v.x; a_s[nl][c0 + 1] = v.y;
    int c2 = (i0 + 2 + sh) & 63;
    a_s[nl][c2] = v.z; a_s[nl][c2 + 1] = v.w;
  }
#pragma unroll
  for (int k = 0; k < 8; ++k) {
    int idx = t + (k << 8);
    int i = idx >> 5, c0 = (idx & 31) << 2;
    int o = o0 + (c0 >> 3);
    int hh = h0 + (c0 & 7);
    *(float4*)&b_s[i][c0] = *(const float4*)&nn2w[((size_t)((i << 6) + o)) * 128 + hh];
  }
  __syncthreads();
  int tx = t & 15, ty = t >> 4;
  float acc[8][8];
#pragma unroll
  for (int r = 0; r < 8; ++r)
#pragma unroll
    for (int c = 0; c < 8; ++c) acc[r][c] = 0.f;
#pragma unroll 4
  for (int i = 0; i < 64; i += 2) {
    float2 a2[8];
#pragma unroll
    for (int r = 0; r < 8; ++r) {
      int row = ty * 8 + r;
      a2[r] = *(const float2*)&a_s[row][(i + 2 * row) & 63];
    }
    float4 b00 = *(const float4*)&b_s[i][tx << 2];
    float4 b01 = *(const float4*)&b_s[i][64 + (tx << 2)];
    float4 b10 = *(const float4*)&b_s[i + 1][tx << 2];
    float4 b11 = *(const float4*)&b_s[i + 1][64 + (tx << 2)];
    const float* p00 = (const float*)&b00;
    const float* p01 = (const float*)&b01;
    const float* p10 = (const float*)&b10;
    const float* p11 = (const float*)&b11;
#pragma unroll
    for (int r = 0; r < 8; ++r) {
      float ax = a2[r].x, ay = a2[r].y;
#pragma unroll
      for (int c = 0; c < 4; ++c) {
        acc[r][c]     = fmaf(ax, p00[c], acc[r][c]);
        acc[r][c]     = fmaf(ay, p10[c], acc[r][c]);
        acc[r][4 + c] = fmaf(ax, p01[c], acc[r][4 + c]);
        acc[r][4 + c] = fmaf(ay, p11[c], acc[r][4 + c]);
      }
    }
  }
  // store: col c=4tx -> o = o0+(tx>>1), h4 = hg*2 + (tx&1); col 64+4tx -> o+8
  float4* V4v = (float4*)V4;
  int h4 = (hg << 1) + (tx & 1);
  int olo = o0 + (tx >> 1);
#pragma unroll
  for (int r = 0; r < 8; ++r) {
    int n = n0 + ty * 8 + r;
    if (n >= N_) continue;
    float4 lo = make_float4(acc[r][0], acc[r][1], acc[r][2], acc[r][3]);
    float4 hi = make_float4(acc[r][4], acc[r][5], acc[r][6], acc[r][7]);
    size_t base = ((size_t)n * H4Cbuf + h4) * 64;
    V4v[base + olo]     = lo;
    V4v[base + olo + 8] = hi;
  }
}

// ---------------- bt[n,o] = sum_i out[n,i]*nn2_b[i*64+o] ----------------
__global__ __launch_bounds__(256) void k_bt(const float* __restrict__ out,
                                            const float* __restrict__ nn2b,
                                            float* __restrict__ bt) {
  __shared__ float os[4][64];
  int n0 = blockIdx.x << 2;
  int tid = threadIdx.x;
  int nl = tid >> 6, o = tid & 63;
  os[nl][o] = out[(size_t)(n0 + nl) * 64 + o];
  __syncthreads();
  float acc = 0.f;
  for (int i = 0; i < 64; ++i) acc += os[nl][i] * nn2b[(i << 6) + o];
  bt[(size_t)(n0 + nl) * 64 + o] = acc;
}

// ---------------- edge contraction, src-grouped, V in registers ----------------
// wave = one src node n; lane = o. v4[h4] = V_chunk[n, h4*4.., o] (1KB-contig
// wave loads). he broadcast via readlane (no LDS). agg via atomics.
template <int H4C>
__global__ __launch_bounds__(256) void k_edge(const float* __restrict__ V4,
                                              const float* __restrict__ he,
                                              const float* __restrict__ bt,
                                              const int* __restrict__ ei,
                                              const int* __restrict__ estart,
                                              const int* __restrict__ eorder,
                                              float* __restrict__ agg,
                                              int hofs) {
  int wid = threadIdx.x >> 6, lane = threadIdx.x & 63;
  int n = blockIdx.x * 4 + wid;
  if (n >= N_) return;
  int se = estart[n], ee = estart[n + 1];
  if (se == ee) return;
  const float4* vp = (const float4*)V4 + (size_t)n * H4C * 64 + lane;
  float4 v4[H4C];
#pragma unroll
  for (int h4 = 0; h4 < H4C; ++h4) v4[h4] = vp[(size_t)h4 * 64];
  float btv = (hofs == 0) ? bt[(size_t)n * 64 + lane] : 0.f;
  constexpr int CWm1 = 4 * H4C - 1;  // chunk width - 1 (<=63 when H4C<=16)
  for (int q = se; q < ee; ++q) {
    int eid = eorder[q];
    int dst = ei[E_ + eid];
    const float* hep = &he[(size_t)eid * H_];
    float hh, hh2 = 0.f;
    if (H4C == 32) { hh = hep[lane]; hh2 = hep[64 + lane]; }
    else           { hh = hep[hofs + (lane & CWm1)]; }
    float acc = btv;
#pragma unroll
    for (int h4 = 0; h4 < H4C; ++h4) {
      const float* vv = (const float*)&v4[h4];
#pragma unroll
      for (int c = 0; c < 4; ++c) {
        int hl = h4 * 4 + c;
        float bh = (hl < 64) ? rdlane(hh, hl) : rdlane(hh2, hl - 64);
        acc = fmaf(bh, vv[c], acc);
      }
    }
    atomicAdd(&agg[(size_t)dst * 64 + lane], acc);
  }
}

// ------- node update: m = relu(agg/deg + out@root + bias); GRU -> nxt ----------
// GRU weights staged in LDS [192][65] (65 = 1 mod 32 -> 2-way, free), two phases.
__global__ __launch_bounds__(256) void k_update(const float* __restrict__ agg,
                                                const float* __restrict__ deg,
                                                const float* __restrict__ cur,
                                                const float* __restrict__ root,
                                                const float* __restrict__ cbias,
                                                const float* __restrict__ wih,
                                                const float* __restrict__ whh,
                                                const float* __restrict__ bih,
                                                const float* __restrict__ bhh,
                                                float* __restrict__ nxt) {
  __shared__ float wsh[192][65];
  __shared__ float outs[4][64];
  __shared__ float ms[4][64];
  int n0 = blockIdx.x << 2;
  int tid = threadIdx.x;
  int nl = tid >> 6, o = tid & 63;
  int n = n0 + nl;
  outs[nl][o] = cur[(size_t)n * 64 + o];
  for (int g = tid; g < 192 * 64; g += 256) wsh[g >> 6][g & 63] = wih[g];
  __syncthreads();
  float dg = deg[n];
  float iv = dg > 0.f ? 1.f / dg : 0.f;
  float acc = agg[(size_t)n * 64 + o] * iv + cbias[o];
  for (int i = 0; i < 64; ++i) acc += outs[nl][i] * root[(i << 6) + o];
  float m = fmaxf(acc, 0.f);
  ms[nl][o] = m;
  __syncthreads();
  float xr = bih[o], xz = bih[64 + o], xn = bih[128 + o];
  for (int i = 0; i < 64; ++i) {
    float mi = ms[nl][i];
    xr += mi * wsh[o][i];
    xz += mi * wsh[64 + o][i];
    xn += mi * wsh[128 + o][i];
  }
  __syncthreads();
  for (int g = tid; g < 192 * 64; g += 256) wsh[g >> 6][g & 63] = whh[g];
  __syncthreads();
  float hr = bhh[o], hz = bhh[64 + o], hn = bhh[128 + o];
  for (int i = 0; i < 64; ++i) {
    float hi = outs[nl][i];
    hr += hi * wsh[o][i];
    hz += hi * wsh[64 + o][i];
    hn += hi * wsh[128 + o][i];
  }
  float rg = sigm(xr + hr);
  float zg = sigm(xz + hz);
  float ng = tanhf(xn + rg * hn);
  nxt[(size_t)n * 64 + o] = (1.f - zg) * ng + zg * outs[nl][o];
}

// ------- Set2Set fused step: LSTM cell + attention pooling (+ final MLP) -------
// One block per graph. gates: one row per thread (256 rows).
__global__ __launch_bounds__(256) void k_s2s(const float* __restrict__ out,
                                             const int* __restrict__ gs,
                                             float* __restrict__ qstar,
                                             float* __restrict__ hs,
                                             float* __restrict__ cs,
                                             const float* __restrict__ wih,
                                             const float* __restrict__ whh,
                                             const float* __restrict__ bih,
                                             const float* __restrict__ bhh,
                                             const float* __restrict__ w1,
                                             const float* __restrict__ b1,
                                             const float* __restrict__ w2,
                                             const float* __restrict__ b2,
                                             float* __restrict__ y, int dofinal) {
  int b = blockIdx.x, tid = threadIdx.x;
  __shared__ float qs[128];
  __shared__ float hss[64];
  __shared__ float gsh[256];
  __shared__ float qv[64];
  __shared__ float rv[64];
  __shared__ float wred[4];
  __shared__ float rred[4][64];
  if (tid < 128) qs[tid] = qstar[b * 128 + tid];
  else if (tid < 192) hss[tid - 128] = hs[b * 64 + (tid - 128)];
  __syncthreads();
  {  // LSTM gates, one row r per thread (i|f|g|o blocks of 64)
    int r = tid;
    float acc = bih[r] + bhh[r];
    for (int k = 0; k < 128; ++k) acc += qs[k] * wih[r * 128 + k];
    for (int k = 0; k < 64; ++k) acc += hss[k] * whh[r * 64 + k];
    gsh[r] = acc;
  }
  __syncthreads();
  if (tid < 64) {
    float ig = sigm(gsh[tid]), fg = sigm(gsh[64 + tid]);
    float gg = tanhf(gsh[128 + tid]), og = sigm(gsh[192 + tid]);
    float c = fg * cs[b * 64 + tid] + ig * gg;
    cs[b * 64 + tid] = c;
    float hv = og * tanhf(c);
    hs[b * 64 + tid] = hv;
    qv[tid] = hv;
  }
  __syncthreads();
  // attention: e_n = <out[n], qv>; softmax over graph; rvec = sum a_n out[n]
  int wid = tid >> 6, l = tid & 63;
  int s = gs[b], e_ = gs[b + 1];
  float wmax = -3.4e38f;
  for (int n = s + wid; n < e_; n += 4) {
    float p = out[(size_t)n * 64 + l] * qv[l];
#pragma unroll
    for (int off = 32; off; off >>= 1) p += __shfl_xor(p, off);
    wmax = fmaxf(wmax, p);
  }
  if (l == 0) wred[wid] = wmax;
  __syncthreads();
  float gmax = fmaxf(fmaxf(wred[0], wred[1]), fmaxf(wred[2], wred[3]));
  __syncthreads();
  float dacc = 0.f, racc = 0.f;
  for (int n = s + wid; n < e_; n += 4) {
    float p = out[(size_t)n * 64 + l] * qv[l];
#pragma unroll
    for (int off = 32; off; off >>= 1) p += __shfl_xor(p, off);
    float ee = __expf(p - gmax);
    dacc += ee;
    racc += ee * out[(size_t)n * 64 + l];
  }
  rred[wid][l] = racc;
  if (l == 0) wred[wid] = dacc;
  __syncthreads();
  if (wid == 0) {
    float denom = wred[0] + wred[1] + wred[2] + wred[3];
    float r = (rred[0][l] + rred[1][l] + rred[2][l] + rred[3][l]) /
              fmaxf(denom, 1e-16f);
    rv[l] = r;
    qstar[b * 128 + l] = qv[l];
    qstar[b * 128 + 64 + l] = r;
  }
  if (dofinal) {
    __syncthreads();
    if (tid < 64) {
      float acc = b1[tid];
      for (int k = 0; k < 64; ++k) acc += qv[k] * w1[tid * 128 + k];
      for (int k = 0; k < 64; ++k) acc += rv[k] * w1[tid * 128 + 64 + k];
      float t1 = fmaxf(acc, 0.f) * w2[tid];
#pragma unroll
      for (int off = 32; off; off >>= 1) t1 += __shfl_xor(t1, off);
      if (tid == 0) y[b] = t1 + b2[0];
    }
  }
}

extern "C" void kernel_launch(void* const* d_in, const int* in_sizes, int n_in,
                              void* d_out, int out_size, void* d_ws, size_t ws_size,
                              hipStream_t stream) {
  const float* x        = (const float*)d_in[0];
  const float* ea       = (const float*)d_in[1];
  const float* lin0_w   = (const float*)d_in[2];
  const float* lin0_b   = (const float*)d_in[3];
  const float* nn1_w    = (const float*)d_in[4];
  const float* nn1_b    = (const float*)d_in[5];
  const float* nn2_w    = (const float*)d_in[6];
  const float* nn2_b    = (const float*)d_in[7];
  const float* root     = (const float*)d_in[8];
  const float* cbias    = (const float*)d_in[9];
  const float* gru_wih  = (const float*)d_in[10];
  const float* gru_whh  = (const float*)d_in[11];
  const float* gru_bih  = (const float*)d_in[12];
  const float* gru_bhh  = (const float*)d_in[13];
  const float* lstm_wih = (const float*)d_in[14];
  const float* lstm_whh = (const float*)d_in[15];
  const float* lstm_bih = (const float*)d_in[16];
  const float* lstm_bhh = (const float*)d_in[17];
  const float* lin1_w   = (const float*)d_in[18];
  const float* lin1_b   = (const float*)d_in[19];
  const float* lin2_w   = (const float*)d_in[20];
  const float* lin2_b   = (const float*)d_in[21];
  const int*   ei       = (const int*)d_in[22];
  const int*   batch    = (const int*)d_in[23];
  float* yout = (float*)d_out;
  (void)n_in; (void)in_sizes; (void)out_size;

  // ---- workspace carve-up (256B aligned); zero-group first (single memset) ----
  size_t off = 0;
  auto carve = [&](size_t bytes) -> void* {
    void* p = (char*)d_ws + off;
    off = (off + bytes + 255) & ~(size_t)255;
    return p;
  };
  float* deg    = (float*)carve((size_t)N_ * 4);
  int*   outcnt = (int*)carve((size_t)N_ * 4);
  float* qstar  = (float*)carve((size_t)B_ * 128 * 4);
  float* hs     = (float*)carve((size_t)B_ * 64 * 4);
  float* cs     = (float*)carve((size_t)B_ * 64 * 4);
  size_t zero_span = off;  // deg is at offset 0
  float* out_a  = (float*)carve((size_t)N_ * DIM_ * 4);
  float* out_b  = (float*)carve((size_t)N_ * DIM_ * 4);
  float* bt     = (float*)carve((size_t)N_ * DIM_ * 4);
  float* agg    = (float*)carve((size_t)N_ * DIM_ * 4);
  int*   estart = (int*)carve((size_t)(N_ + 1) * 4);
  int*   cursor = (int*)carve((size_t)N_ * 4);
  int*   eorder = (int*)carve((size_t)E_ * 4);
  int*   gs     = (int*)carve((size_t)(B_ + 1) * 4);
  float* he     = (float*)carve((size_t)E_ * H_ * 4);
  size_t common = off;
  // ---- pick largest h-chunk width that fits ws ----
  int CW = 8;
  {
    const int cws[5] = {128, 64, 32, 16, 8};
    for (int i = 0; i < 5; ++i) {
      size_t vb = (size_t)N_ * cws[i] * 64 * 4;
      if (common + vb <= ws_size) { CW = cws[i]; break; }
    }
  }
  float* V4 = (float*)carve((size_t)N_ * CW * 64 * 4);
  int nchunks = 128 / CW;
  int lwHg = __builtin_ctz(CW >> 3);  // log2(CW/8)
  int H4Cb = CW / 4;

  // ---- init ----
  hipMemsetAsync(d_ws, 0, zero_span, stream);

  k_lin0<<<N_ / 4, 256, 0, stream>>>(x, lin0_w, lin0_b, out_a);
  k_he<<<E_ / 32, 256, 0, stream>>>(ea, nn1_w, nn1_b, he);
  k_hist<<<(E_ + 255) / 256, 256, 0, stream>>>(ei, outcnt, deg);
  k_scan<<<1, 1024, 0, stream>>>(outcnt, estart, cursor);
  k_scatter<<<(E_ + 255) / 256, 256, 0, stream>>>(ei, cursor, eorder);
  k_gstart<<<(N_ + 255) / 256, 256, 0, stream>>>(batch, gs);

  // ---- 2 conv+GRU steps ----
  float* cur = out_a;
  float* nxt = out_b;
  int ntile = (N_ + 127) / 128;  // 79
  dim3 vg(ntile, 4 << lwHg);
  int egrid = (N_ + 3) / 4;
  for (int t = 0; t < 2; ++t) {
    hipMemsetAsync(agg, 0, (size_t)N_ * DIM_ * 4, stream);
    k_bt<<<N_ / 4, 256, 0, stream>>>(cur, nn2_b, bt);
    for (int chunk = 0; chunk < nchunks; ++chunk) {
      int h_base = chunk * CW;
      k_vgemm<<<vg, 256, 0, stream>>>(cur, nn2_w, V4, h_base, H4Cb, lwHg);
      switch (CW) {
        case 128: k_edge<32><<<egrid, 256, 0, stream>>>(V4, he, bt, ei, estart, eorder, agg, h_base); break;
        case 64:  k_edge<16><<<egrid, 256, 0, stream>>>(V4, he, bt, ei, estart, eorder, agg, h_base); break;
        case 32:  k_edge<8><<<egrid, 256, 0, stream>>>(V4, he, bt, ei, estart, eorder, agg, h_base); break;
        case 16:  k_edge<4><<<egrid, 256, 0, stream>>>(V4, he, bt, ei, estart, eorder, agg, h_base); break;
        default:  k_edge<2><<<egrid, 256, 0, stream>>>(V4, he, bt, ei, estart, eorder, agg, h_base); break;
      }
    }
    k_update<<<N_ / 4, 256, 0, stream>>>(agg, deg, cur, root, cbias,
                                         gru_wih, gru_whh, gru_bih, gru_bhh, nxt);
    float* tmp = cur; cur = nxt; nxt = tmp;
  }

  // ---- Set2Set (2 fused steps; final MLP folded into step 2) ----
  k_s2s<<<B_, 256, 0, stream>>>(cur, gs, qstar, hs, cs, lstm_wih, lstm_whh,
                                lstm_bih, lstm_bhh, lin1_w, lin1_b, lin2_w,
                                lin2_b, yout, 0);
  k_s2s<<<B_, 256, 0, stream>>>(cur, gs, qstar, hs, cs, lstm_wih, lstm_whh,
                                lstm_bih, lstm_bhh, lin1_w, lin1_b, lin2_w,
                                lin2_b, yout, 1);
}

// Round 5
// 908.554 us; speedup vs baseline: 1.1054x; 1.1054x over previous
//
#include <hip/hip_runtime.h>
#include <hip/hip_bf16.h>

// Problem sizes (fixed)
#define N_   10000
#define E_   100000
#define B_   64
#define DIM_ 64
#define NF_  92
#define EF_  50
#define H_   128

typedef unsigned int u32;

__device__ __forceinline__ float sigm(float x) { return 1.f / (1.f + __expf(-x)); }
__device__ __forceinline__ float rdlane(float v, int l) {
  return __uint_as_float(__builtin_amdgcn_readlane(__float_as_uint(v), l));
}

// ---------------- lin0: out = relu(x @ lin0_w.T + b)  [N, DIM] ----------------
__global__ __launch_bounds__(256) void k_lin0(const float* __restrict__ x,
                                              const float* __restrict__ w,
                                              const float* __restrict__ b,
                                              float* __restrict__ out) {
  __shared__ float xs[4][NF_];
  __shared__ float w_s[DIM_][93];
  int n0 = blockIdx.x << 2;
  int tid = threadIdx.x;
  for (int k = tid; k < 4 * NF_; k += 256) {
    int nl = k / NF_, f = k % NF_;
    xs[nl][f] = x[(size_t)(n0 + nl) * NF_ + f];
  }
  for (int g = tid; g < DIM_ * NF_; g += 256) {
    int d = g / NF_, f = g % NF_;
    w_s[d][f] = w[g];
  }
  __syncthreads();
  int nl = tid >> 6, d = tid & 63;
  float acc = b[d];
  for (int f = 0; f < NF_; ++f) acc += xs[nl][f] * w_s[d][f];
  out[(size_t)(n0 + nl) * DIM_ + d] = fmaxf(acc, 0.f);
}

// ---------------- he = relu(edge_attr @ nn1_w.T + b)  [E, H] ----------------
__global__ __launch_bounds__(256) void k_he(const float* __restrict__ ea,
                                            const float* __restrict__ w,
                                            const float* __restrict__ b,
                                            float* __restrict__ he) {
  __shared__ float wt[EF_][132];  // wt[f][h]
  __shared__ float es[32][52];    // es[e][f]
  int e0 = blockIdx.x * 32, t = threadIdx.x;
  for (int g = t; g < H_ * EF_; g += 256) {
    int h = g / EF_, f = g % EF_;
    wt[f][h] = w[g];
  }
  for (int g = t; g < 32 * EF_; g += 256) {
    int e = g / EF_, f = g % EF_;
    es[e][f] = ea[(size_t)(e0 + e) * EF_ + f];
  }
  __syncthreads();
  int h0 = (t & 31) << 2, eg = t >> 5;  // eg in [0,8): 4 edges each
  float acc[4][4];
#pragma unroll
  for (int j = 0; j < 4; ++j)
#pragma unroll
    for (int c = 0; c < 4; ++c) acc[j][c] = b[h0 + c];
  for (int f = 0; f < EF_; ++f) {
    float4 wv = *(const float4*)&wt[f][h0];
    const float* wp = (const float*)&wv;
#pragma unroll
    for (int j = 0; j < 4; ++j) {
      float ev = es[eg * 4 + j][f];
#pragma unroll
      for (int c = 0; c < 4; ++c) acc[j][c] = fmaf(ev, wp[c], acc[j][c]);
    }
  }
#pragma unroll
  for (int j = 0; j < 4; ++j) {
    float4 o;
    o.x = fmaxf(acc[j][0], 0.f); o.y = fmaxf(acc[j][1], 0.f);
    o.z = fmaxf(acc[j][2], 0.f); o.w = fmaxf(acc[j][3], 0.f);
    *(float4*)&he[(size_t)(e0 + eg * 4 + j) * H_ + h0] = o;
  }
}

// ------------- histograms: out-degree (int, by src), in-degree (float, by dst) --
__global__ __launch_bounds__(256) void k_hist(const int* __restrict__ ei,
                                              int* __restrict__ outcnt,
                                              float* __restrict__ degf) {
  int e = blockIdx.x * 256 + threadIdx.x;
  if (e < E_) {
    atomicAdd(&outcnt[ei[e]], 1);
    atomicAdd(&degf[ei[E_ + e]], 1.0f);
  }
}

// ------------- exclusive scan of outcnt -> estart[N+1], cursor ----------------
__global__ __launch_bounds__(1024) void k_scan(const int* __restrict__ outcnt,
                                               int* __restrict__ estart,
                                               int* __restrict__ cursor) {
  __shared__ int part[1024];
  int t = threadIdx.x;
  int base = t * 10;
  int c[10];
  int s = 0;
#pragma unroll
  for (int j = 0; j < 10; ++j) {
    int idx = base + j;
    c[j] = (idx < N_) ? outcnt[idx] : 0;
    s += c[j];
  }
  part[t] = s;
  __syncthreads();
  for (int off = 1; off < 1024; off <<= 1) {
    int v = (t >= off) ? part[t - off] : 0;
    __syncthreads();
    part[t] += v;
    __syncthreads();
  }
  int ex = (t > 0) ? part[t - 1] : 0;
#pragma unroll
  for (int j = 0; j < 10; ++j) {
    int idx = base + j;
    if (idx < N_) { estart[idx] = ex; cursor[idx] = ex; }
    ex += c[j];
  }
  if (t == 1023) estart[N_] = part[1023];
}

// ---------------- scatter: eorder grouped by src ----------------
__global__ __launch_bounds__(256) void k_scatter(const int* __restrict__ ei,
                                                 int* __restrict__ cursor,
                                                 int* __restrict__ eorder) {
  int e = blockIdx.x * 256 + threadIdx.x;
  if (e < E_) {
    int s = ei[e];
    int pos = atomicAdd(&cursor[s], 1);
    eorder[pos] = e;
  }
}

// ---------------- graph start offsets from sorted batch ----------------
__global__ __launch_bounds__(256) void k_gstart(const int* __restrict__ batch,
                                                int* __restrict__ gs) {
  int n = blockIdx.x * 256 + threadIdx.x;
  if (n >= N_) return;
  int b = batch[n];
  if (n == 0) {
    for (int bb = 0; bb <= b; ++bb) gs[bb] = 0;
  } else {
    int pb = batch[n - 1];
    if (pb != b)
      for (int bb = pb + 1; bb <= b; ++bb) gs[bb] = n;
  }
  if (n == N_ - 1) {
    for (int bb = b + 1; bb <= B_; ++bb) gs[bb] = N_;
  }
}

// ------- weight transposes (once per call): GRU 192x64 -> [i][r]; LSTM too ----
__global__ __launch_bounds__(256) void k_transpose(const float* __restrict__ gih,
                                                   const float* __restrict__ ghh,
                                                   const float* __restrict__ lih,
                                                   const float* __restrict__ lhh,
                                                   float* __restrict__ gihT,
                                                   float* __restrict__ ghhT,
                                                   float* __restrict__ lihT,
                                                   float* __restrict__ lhhT) {
  int idx = blockIdx.x * 256 + threadIdx.x;
  if (idx < 192 * 64) {
    int r = idx >> 6, i = idx & 63;
    gihT[i * 192 + r] = gih[idx];
    ghhT[i * 192 + r] = ghh[idx];
  }
  if (idx < 256 * 128) {
    int r = idx >> 7, k = idx & 127;
    lihT[k * 256 + r] = lih[idx];
  }
  if (idx < 256 * 64) {
    int r = idx >> 6, k = idx & 63;
    lhhT[k * 256 + r] = lhh[idx];
  }
}

// ---------------- V-GEMM: V[n,h,o] = sum_i out[n,i]*nn2_w[(i*64+o)*128+h] -------
__global__ __launch_bounds__(256) void k_vgemm(const float* __restrict__ outv,
                                               const float* __restrict__ nn2w,
                                               float* __restrict__ V4,
                                               int h_base, int H4Cbuf, int lwHg) {
  __shared__ float a_s[128][64];  // [node][i swizzled]
  __shared__ float b_s[64][128];  // [i][col]
  int n0 = blockIdx.x << 7;
  int og = blockIdx.y >> lwHg;
  int hg = blockIdx.y & ((1 << lwHg) - 1);
  int o0 = og << 4;
  int h0 = h_base + (hg << 3);
  int t = threadIdx.x;
#pragma unroll
  for (int k = 0; k < 8; ++k) {
    int idx = t + (k << 8);          // 0..2047
    int nl = idx >> 4, i0 = (idx & 15) << 2;
    float4 v = make_float4(0.f, 0.f, 0.f, 0.f);
    int n = n0 + nl;
    if (n < N_) v = *(const float4*)&outv[(size_t)n * 64 + i0];
    int sh = 2 * nl;
    int c0 = (i0 + sh) & 63;
    a_s[nl][c0] = v.x; a_s[nl][c0 + 1] = v.y;
    int c2 = (i0 + 2 + sh) & 63;
    a_s[nl][c2] = v.z; a_s[nl][c2 + 1] = v.w;
  }
#pragma unroll
  for (int k = 0; k < 8; ++k) {
    int idx = t + (k << 8);
    int i = idx >> 5, c0 = (idx & 31) << 2;
    int o = o0 + (c0 >> 3);
    int hh = h0 + (c0 & 7);
    *(float4*)&b_s[i][c0] = *(const float4*)&nn2w[((size_t)((i << 6) + o)) * 128 + hh];
  }
  __syncthreads();
  int tx = t & 15, ty = t >> 4;
  float acc[8][8];
#pragma unroll
  for (int r = 0; r < 8; ++r)
#pragma unroll
    for (int c = 0; c < 8; ++c) acc[r][c] = 0.f;
#pragma unroll 4
  for (int i = 0; i < 64; i += 2) {
    float2 a2[8];
#pragma unroll
    for (int r = 0; r < 8; ++r) {
      int row = ty * 8 + r;
      a2[r] = *(const float2*)&a_s[row][(i + 2 * row) & 63];
    }
    float4 b00 = *(const float4*)&b_s[i][tx << 2];
    float4 b01 = *(const float4*)&b_s[i][64 + (tx << 2)];
    float4 b10 = *(const float4*)&b_s[i + 1][tx << 2];
    float4 b11 = *(const float4*)&b_s[i + 1][64 + (tx << 2)];
    const float* p00 = (const float*)&b00;
    const float* p01 = (const float*)&b01;
    const float* p10 = (const float*)&b10;
    const float* p11 = (const float*)&b11;
#pragma unroll
    for (int r = 0; r < 8; ++r) {
      float ax = a2[r].x, ay = a2[r].y;
#pragma unroll
      for (int c = 0; c < 4; ++c) {
        acc[r][c]     = fmaf(ax, p00[c], acc[r][c]);
        acc[r][c]     = fmaf(ay, p10[c], acc[r][c]);
        acc[r][4 + c] = fmaf(ax, p01[c], acc[r][4 + c]);
        acc[r][4 + c] = fmaf(ay, p11[c], acc[r][4 + c]);
      }
    }
  }
  float4* V4v = (float4*)V4;
  int h4 = (hg << 1) + (tx & 1);
  int olo = o0 + (tx >> 1);
#pragma unroll
  for (int r = 0; r < 8; ++r) {
    int n = n0 + ty * 8 + r;
    if (n >= N_) continue;
    float4 lo = make_float4(acc[r][0], acc[r][1], acc[r][2], acc[r][3]);
    float4 hi = make_float4(acc[r][4], acc[r][5], acc[r][6], acc[r][7]);
    size_t base = ((size_t)n * H4Cbuf + h4) * 64;
    V4v[base + olo]     = lo;
    V4v[base + olo + 8] = hi;
  }
}

// ---------------- bt[n,o] = sum_i out[n,i]*nn2_b[i*64+o] ----------------
__global__ __launch_bounds__(256) void k_bt(const float* __restrict__ out,
                                            const float* __restrict__ nn2b,
                                            float* __restrict__ bt) {
  __shared__ float os[4][64];
  int n0 = blockIdx.x << 2;
  int tid = threadIdx.x;
  int nl = tid >> 6, o = tid & 63;
  os[nl][o] = out[(size_t)(n0 + nl) * 64 + o];
  __syncthreads();
  float acc = 0.f;
  for (int i = 0; i < 64; ++i) acc += os[nl][i] * nn2b[(i << 6) + o];
  bt[(size_t)(n0 + nl) * 64 + o] = acc;
}

// ---------------- edge contraction, src-grouped, V in registers ----------------
template <int H4C>
__global__ __launch_bounds__(256) void k_edge(const float* __restrict__ V4,
                                              const float* __restrict__ he,
                                              const float* __restrict__ bt,
                                              const int* __restrict__ ei,
                                              const int* __restrict__ estart,
                                              const int* __restrict__ eorder,
                                              float* __restrict__ agg,
                                              int hofs) {
  int wid = threadIdx.x >> 6, lane = threadIdx.x & 63;
  int n = blockIdx.x * 4 + wid;
  if (n >= N_) return;
  int se = estart[n], ee = estart[n + 1];
  if (se == ee) return;
  const float4* vp = (const float4*)V4 + (size_t)n * H4C * 64 + lane;
  float4 v4[H4C];
#pragma unroll
  for (int h4 = 0; h4 < H4C; ++h4) v4[h4] = vp[(size_t)h4 * 64];
  float btv = (hofs == 0) ? bt[(size_t)n * 64 + lane] : 0.f;
  constexpr int CWm1 = 4 * H4C - 1;
  for (int q = se; q < ee; ++q) {
    int eid = eorder[q];
    int dst = ei[E_ + eid];
    const float* hep = &he[(size_t)eid * H_];
    float hh, hh2 = 0.f;
    if (H4C == 32) { hh = hep[lane]; hh2 = hep[64 + lane]; }
    else           { hh = hep[hofs + (lane & CWm1)]; }
    float acc = btv;
#pragma unroll
    for (int h4 = 0; h4 < H4C; ++h4) {
      const float* vv = (const float*)&v4[h4];
#pragma unroll
      for (int c = 0; c < 4; ++c) {
        int hl = h4 * 4 + c;
        float bh = (hl < 64) ? rdlane(hh, hl) : rdlane(hh2, hl - 64);
        acc = fmaf(bh, vv[c], acc);
      }
    }
    atomicAdd(&agg[(size_t)dst * 64 + lane], acc);
  }
}

// ------- node update: m = relu(agg/deg + out@root + cbias); GRU -> nxt ----------
// 32 nodes/block, lane=o, 8 nodes/thread in registers. Weights pre-transposed
// ([i][r], coalesced 256B per load, L1-hot). Node vectors via LDS broadcast.
__global__ __launch_bounds__(256) void k_update(const float* __restrict__ agg,
                                                const float* __restrict__ deg,
                                                const float* __restrict__ cur,
                                                const float* __restrict__ root,
                                                const float* __restrict__ cbias,
                                                const float* __restrict__ wihT,
                                                const float* __restrict__ whhT,
                                                const float* __restrict__ bih,
                                                const float* __restrict__ bhh,
                                                float* __restrict__ nxt) {
  __shared__ float outs[32][64];
  __shared__ float ms[32][64];
  int n0 = blockIdx.x << 5;
  int tid = threadIdx.x;
  int o = tid & 63, g = tid >> 6;
#pragma unroll
  for (int k = 0; k < 8; ++k) {
    int idx = tid + (k << 8);
    int nl = idx >> 6, i = idx & 63;
    int n = n0 + nl;
    outs[nl][i] = (n < N_) ? cur[(size_t)n * 64 + i] : 0.f;
  }
  __syncthreads();
  // phase 1: m = relu(agg/deg + out@root + cbias)
  float acc[8];
  float cb = cbias[o];
#pragma unroll
  for (int j = 0; j < 8; ++j) {
    int n = n0 + (g << 3) + j;
    if (n < N_) {
      float dg = deg[n];
      float iv = dg > 0.f ? 1.f / dg : 0.f;
      acc[j] = agg[(size_t)n * 64 + o] * iv + cb;
    } else acc[j] = 0.f;
  }
  for (int i = 0; i < 64; ++i) {
    float r = root[(i << 6) + o];
#pragma unroll
    for (int j = 0; j < 8; ++j) acc[j] = fmaf(outs[(g << 3) + j][i], r, acc[j]);
  }
#pragma unroll
  for (int j = 0; j < 8; ++j) ms[(g << 3) + j][o] = fmaxf(acc[j], 0.f);
  __syncthreads();
  // phase 2: GRU gates via transposed weights
  float xr[8], xz[8], xn[8], hr[8], hz[8], hn[8];
  {
    float br = bih[o], bz = bih[64 + o], bn = bih[128 + o];
    float dr = bhh[o], dz = bhh[64 + o], dn = bhh[128 + o];
#pragma unroll
    for (int j = 0; j < 8; ++j) {
      xr[j] = br; xz[j] = bz; xn[j] = bn;
      hr[j] = dr; hz[j] = dz; hn[j] = dn;
    }
  }
  for (int i = 0; i < 64; ++i) {
    const float* wi = &wihT[i * 192];
    const float* vi = &whhT[i * 192];
    float w0 = wi[o], w1 = wi[64 + o], w2 = wi[128 + o];
    float v0 = vi[o], v1 = vi[64 + o], v2 = vi[128 + o];
#pragma unroll
    for (int j = 0; j < 8; ++j) {
      int nl = (g << 3) + j;
      float mi = ms[nl][i], hi = outs[nl][i];
      xr[j] = fmaf(mi, w0, xr[j]);
      xz[j] = fmaf(mi, w1, xz[j]);
      xn[j] = fmaf(mi, w2, xn[j]);
      hr[j] = fmaf(hi, v0, hr[j]);
      hz[j] = fmaf(hi, v1, hz[j]);
      hn[j] = fmaf(hi, v2, hn[j]);
    }
  }
#pragma unroll
  for (int j = 0; j < 8; ++j) {
    int nl = (g << 3) + j;
    int n = n0 + nl;
    if (n < N_) {
      float rg = sigm(xr[j] + hr[j]);
      float zg = sigm(xz[j] + hz[j]);
      float ng = tanhf(xn[j] + rg * hn[j]);
      nxt[(size_t)n * 64 + o] = (1.f - zg) * ng + zg * outs[nl][o];
    }
  }
}

// ------- Set2Set fused step: LSTM cell + attention pooling (+ final MLP) -------
__global__ __launch_bounds__(256) void k_s2s(const float* __restrict__ out,
                                             const int* __restrict__ gs,
                                             float* __restrict__ qstar,
                                             float* __restrict__ hs,
                                             float* __restrict__ cs,
                                             const float* __restrict__ lihT,
                                             const float* __restrict__ lhhT,
                                             const float* __restrict__ bih,
                                             const float* __restrict__ bhh,
                                             const float* __restrict__ w1,
                                             const float* __restrict__ b1,
                                             const float* __restrict__ w2,
                                             const float* __restrict__ b2,
                                             float* __restrict__ y, int dofinal) {
  int b = blockIdx.x, tid = threadIdx.x;
  __shared__ float qs[128];
  __shared__ float hss[64];
  __shared__ float gsh[256];
  __shared__ float qv[64];
  __shared__ float rv[64];
  __shared__ float wred[4];
  __shared__ float rred[4][64];
  if (tid < 128) qs[tid] = qstar[b * 128 + tid];
  else if (tid < 192) hss[tid - 128] = hs[b * 64 + (tid - 128)];
  __syncthreads();
  {  // LSTM gates, one row per thread; transposed weights (coalesced)
    int r = tid;
    float acc = bih[r] + bhh[r];
    for (int k = 0; k < 128; ++k) acc += qs[k] * lihT[k * 256 + r];
    for (int k = 0; k < 64; ++k) acc += hss[k] * lhhT[k * 256 + r];
    gsh[r] = acc;
  }
  __syncthreads();
  if (tid < 64) {
    float ig = sigm(gsh[tid]), fg = sigm(gsh[64 + tid]);
    float gg = tanhf(gsh[128 + tid]), og = sigm(gsh[192 + tid]);
    float c = fg * cs[b * 64 + tid] + ig * gg;
    cs[b * 64 + tid] = c;
    float hv = og * tanhf(c);
    hs[b * 64 + tid] = hv;
    qv[tid] = hv;
  }
  __syncthreads();
  int wid = tid >> 6, l = tid & 63;
  int s = gs[b], e_ = gs[b + 1];
  float wmax = -3.4e38f;
  for (int n = s + wid; n < e_; n += 4) {
    float p = out[(size_t)n * 64 + l] * qv[l];
#pragma unroll
    for (int off = 32; off; off >>= 1) p += __shfl_xor(p, off);
    wmax = fmaxf(wmax, p);
  }
  if (l == 0) wred[wid] = wmax;
  __syncthreads();
  float gmax = fmaxf(fmaxf(wred[0], wred[1]), fmaxf(wred[2], wred[3]));
  __syncthreads();
  float dacc = 0.f, racc = 0.f;
  for (int n = s + wid; n < e_; n += 4) {
    float p = out[(size_t)n * 64 + l] * qv[l];
#pragma unroll
    for (int off = 32; off; off >>= 1) p += __shfl_xor(p, off);
    float ee = __expf(p - gmax);
    dacc += ee;
    racc += ee * out[(size_t)n * 64 + l];
  }
  rred[wid][l] = racc;
  if (l == 0) wred[wid] = dacc;
  __syncthreads();
  if (wid == 0) {
    float denom = wred[0] + wred[1] + wred[2] + wred[3];
    float r = (rred[0][l] + rred[1][l] + rred[2][l] + rred[3][l]) /
              fmaxf(denom, 1e-16f);
    rv[l] = r;
    qstar[b * 128 + l] = qv[l];
    qstar[b * 128 + 64 + l] = r;
  }
  if (dofinal) {
    __syncthreads();
    if (tid < 64) {
      float acc = b1[tid];
      for (int k = 0; k < 64; ++k) acc += qv[k] * w1[tid * 128 + k];
      for (int k = 0; k < 64; ++k) acc += rv[k] * w1[tid * 128 + 64 + k];
      float t1 = fmaxf(acc, 0.f) * w2[tid];
#pragma unroll
      for (int off = 32; off; off >>= 1) t1 += __shfl_xor(t1, off);
      if (tid == 0) y[b] = t1 + b2[0];
    }
  }
}

extern "C" void kernel_launch(void* const* d_in, const int* in_sizes, int n_in,
                              void* d_out, int out_size, void* d_ws, size_t ws_size,
                              hipStream_t stream) {
  const float* x        = (const float*)d_in[0];
  const float* ea       = (const float*)d_in[1];
  const float* lin0_w   = (const float*)d_in[2];
  const float* lin0_b   = (const float*)d_in[3];
  const float* nn1_w    = (const float*)d_in[4];
  const float* nn1_b    = (const float*)d_in[5];
  const float* nn2_w    = (const float*)d_in[6];
  const float* nn2_b    = (const float*)d_in[7];
  const float* root     = (const float*)d_in[8];
  const float* cbias    = (const float*)d_in[9];
  const float* gru_wih  = (const float*)d_in[10];
  const float* gru_whh  = (const float*)d_in[11];
  const float* gru_bih  = (const float*)d_in[12];
  const float* gru_bhh  = (const float*)d_in[13];
  const float* lstm_wih = (const float*)d_in[14];
  const float* lstm_whh = (const float*)d_in[15];
  const float* lstm_bih = (const float*)d_in[16];
  const float* lstm_bhh = (const float*)d_in[17];
  const float* lin1_w   = (const float*)d_in[18];
  const float* lin1_b   = (const float*)d_in[19];
  const float* lin2_w   = (const float*)d_in[20];
  const float* lin2_b   = (const float*)d_in[21];
  const int*   ei       = (const int*)d_in[22];
  const int*   batch    = (const int*)d_in[23];
  float* yout = (float*)d_out;
  (void)n_in; (void)in_sizes; (void)out_size;

  // ---- workspace carve-up (256B aligned); zero-group first (single memset) ----
  size_t off = 0;
  auto carve = [&](size_t bytes) -> void* {
    void* p = (char*)d_ws + off;
    off = (off + bytes + 255) & ~(size_t)255;
    return p;
  };
  float* deg    = (float*)carve((size_t)N_ * 4);
  int*   outcnt = (int*)carve((size_t)N_ * 4);
  float* qstar  = (float*)carve((size_t)B_ * 128 * 4);
  float* hs     = (float*)carve((size_t)B_ * 64 * 4);
  float* cs     = (float*)carve((size_t)B_ * 64 * 4);
  size_t zero_span = off;
  float* out_a  = (float*)carve((size_t)N_ * DIM_ * 4);
  float* out_b  = (float*)carve((size_t)N_ * DIM_ * 4);
  float* bt     = (float*)carve((size_t)N_ * DIM_ * 4);
  float* agg    = (float*)carve((size_t)N_ * DIM_ * 4);
  int*   estart = (int*)carve((size_t)(N_ + 1) * 4);
  int*   cursor = (int*)carve((size_t)N_ * 4);
  int*   eorder = (int*)carve((size_t)E_ * 4);
  int*   gs     = (int*)carve((size_t)(B_ + 1) * 4);
  float* gihT   = (float*)carve((size_t)192 * 64 * 4);
  float* ghhT   = (float*)carve((size_t)192 * 64 * 4);
  float* lihT   = (float*)carve((size_t)256 * 128 * 4);
  float* lhhT   = (float*)carve((size_t)256 * 64 * 4);
  float* he     = (float*)carve((size_t)E_ * H_ * 4);
  size_t common = off;
  // ---- h-chunk width: cap at 64 so V (164 MB) + he (51 MB) stay L3-resident ----
  int CW = 8;
  {
    const int cws[4] = {64, 32, 16, 8};
    for (int i = 0; i < 4; ++i) {
      size_t vb = (size_t)N_ * cws[i] * 64 * 4;
      if (common + vb <= ws_size) { CW = cws[i]; break; }
    }
  }
  float* V4 = (float*)carve((size_t)N_ * CW * 64 * 4);
  int nchunks = 128 / CW;
  int lwHg = __builtin_ctz(CW >> 3);
  int H4Cb = CW / 4;

  // ---- init ----
  hipMemsetAsync(d_ws, 0, zero_span, stream);

  k_lin0<<<N_ / 4, 256, 0, stream>>>(x, lin0_w, lin0_b, out_a);
  k_he<<<E_ / 32, 256, 0, stream>>>(ea, nn1_w, nn1_b, he);
  k_hist<<<(E_ + 255) / 256, 256, 0, stream>>>(ei, outcnt, deg);
  k_scan<<<1, 1024, 0, stream>>>(outcnt, estart, cursor);
  k_scatter<<<(E_ + 255) / 256, 256, 0, stream>>>(ei, cursor, eorder);
  k_gstart<<<(N_ + 255) / 256, 256, 0, stream>>>(batch, gs);
  k_transpose<<<128, 256, 0, stream>>>(gru_wih, gru_whh, lstm_wih, lstm_whh,
                                       gihT, ghhT, lihT, lhhT);

  // ---- 2 conv+GRU steps ----
  float* cur = out_a;
  float* nxt = out_b;
  int ntile = (N_ + 127) / 128;  // 79
  dim3 vg(ntile, 4 << lwHg);
  int egrid = (N_ + 3) / 4;
  for (int t = 0; t < 2; ++t) {
    hipMemsetAsync(agg, 0, (size_t)N_ * DIM_ * 4, stream);
    k_bt<<<N_ / 4, 256, 0, stream>>>(cur, nn2_b, bt);
    for (int chunk = 0; chunk < nchunks; ++chunk) {
      int h_base = chunk * CW;
      k_vgemm<<<vg, 256, 0, stream>>>(cur, nn2_w, V4, h_base, H4Cb, lwHg);
      switch (CW) {
        case 64:  k_edge<16><<<egrid, 256, 0, stream>>>(V4, he, bt, ei, estart, eorder, agg, h_base); break;
        case 32:  k_edge<8><<<egrid, 256, 0, stream>>>(V4, he, bt, ei, estart, eorder, agg, h_base); break;
        case 16:  k_edge<4><<<egrid, 256, 0, stream>>>(V4, he, bt, ei, estart, eorder, agg, h_base); break;
        default:  k_edge<2><<<egrid, 256, 0, stream>>>(V4, he, bt, ei, estart, eorder, agg, h_base); break;
      }
    }
    k_update<<<(N_ + 31) / 32, 256, 0, stream>>>(agg, deg, cur, root, cbias,
                                                 gihT, ghhT, gru_bih, gru_bhh, nxt);
    float* tmp = cur; cur = nxt; nxt = tmp;
  }

  // ---- Set2Set (2 fused steps; final MLP folded into step 2) ----
  k_s2s<<<B_, 256, 0, stream>>>(cur, gs, qstar, hs, cs, lihT, lhhT,
                                lstm_bih, lstm_bhh, lin1_w, lin1_b, lin2_w,
                                lin2_b, yout, 0);
  k_s2s<<<B_, 256, 0, stream>>>(cur, gs, qstar, hs, cs, lihT, lhhT,
                                lstm_bih, lstm_bhh, lin1_w, lin1_b, lin2_w,
                                lin2_b, yout, 1);
}

// Round 8
// 817.820 us; speedup vs baseline: 1.2281x; 1.1109x over previous
//
#include <hip/hip_runtime.h>
#include <hip/hip_bf16.h>

// Problem sizes (fixed)
#define N_   10000
#define E_   100000
#define B_   64
#define DIM_ 64
#define NF_  92
#define EF_  50
#define H_   128
#define NPAD 10048   // 157 * 64, padded node count for MFMA tiles

typedef unsigned int u32;
typedef unsigned short u16;
typedef __attribute__((ext_vector_type(8))) short s16x8;   // 8 bf16 (4 VGPRs)
typedef __attribute__((ext_vector_type(4))) float f32x4;

__device__ __forceinline__ float sigm(float x) { return 1.f / (1.f + __expf(-x)); }
__device__ __forceinline__ float rdlane(float v, int l) {
  return __uint_as_float(__builtin_amdgcn_readlane(__float_as_uint(v), l));
}
__device__ __forceinline__ float bf2f(u16 u) {
  return __uint_as_float(((u32)u) << 16);
}
__device__ __forceinline__ u16 f2bf(float f) {
  u32 u = __float_as_uint(f);
  u32 r = (u + 0x7FFFu + ((u >> 16) & 1u)) >> 16;
  return (u16)r;
}

// ---------------- lin0: out = relu(x @ lin0_w.T + b)  [N, DIM] ----------------
__global__ __launch_bounds__(256) void k_lin0(const float* __restrict__ x,
                                              const float* __restrict__ w,
                                              const float* __restrict__ b,
                                              float* __restrict__ out) {
  __shared__ float xs[4][NF_];
  __shared__ float w_s[DIM_][93];
  int n0 = blockIdx.x << 2;
  int tid = threadIdx.x;
  for (int k = tid; k < 4 * NF_; k += 256) {
    int nl = k / NF_, f = k % NF_;
    xs[nl][f] = x[(size_t)(n0 + nl) * NF_ + f];
  }
  for (int g = tid; g < DIM_ * NF_; g += 256) {
    int d = g / NF_, f = g % NF_;
    w_s[d][f] = w[g];
  }
  __syncthreads();
  int nl = tid >> 6, d = tid & 63;
  float acc = b[d];
  for (int f = 0; f < NF_; ++f) acc += xs[nl][f] * w_s[d][f];
  out[(size_t)(n0 + nl) * DIM_ + d] = fmaxf(acc, 0.f);
}

// ---------------- he = relu(edge_attr @ nn1_w.T + b)  [E, H] ----------------
__global__ __launch_bounds__(256) void k_he(const float* __restrict__ ea,
                                            const float* __restrict__ w,
                                            const float* __restrict__ b,
                                            float* __restrict__ he) {
  __shared__ float wt[EF_][132];  // wt[f][h]
  __shared__ float es[32][52];    // es[e][f]
  int e0 = blockIdx.x * 32, t = threadIdx.x;
  for (int g = t; g < H_ * EF_; g += 256) {
    int h = g / EF_, f = g % EF_;
    wt[f][h] = w[g];
  }
  for (int g = t; g < 32 * EF_; g += 256) {
    int e = g / EF_, f = g % EF_;
    es[e][f] = ea[(size_t)(e0 + e) * EF_ + f];
  }
  __syncthreads();
  int h0 = (t & 31) << 2, eg = t >> 5;  // eg in [0,8): 4 edges each
  float acc[4][4];
#pragma unroll
  for (int j = 0; j < 4; ++j)
#pragma unroll
    for (int c = 0; c < 4; ++c) acc[j][c] = b[h0 + c];
  for (int f = 0; f < EF_; ++f) {
    float4 wv = *(const float4*)&wt[f][h0];
    const float* wp = (const float*)&wv;
#pragma unroll
    for (int j = 0; j < 4; ++j) {
      float ev = es[eg * 4 + j][f];
#pragma unroll
      for (int c = 0; c < 4; ++c) acc[j][c] = fmaf(ev, wp[c], acc[j][c]);
    }
  }
#pragma unroll
  for (int j = 0; j < 4; ++j) {
    float4 o;
    o.x = fmaxf(acc[j][0], 0.f); o.y = fmaxf(acc[j][1], 0.f);
    o.z = fmaxf(acc[j][2], 0.f); o.w = fmaxf(acc[j][3], 0.f);
    *(float4*)&he[(size_t)(e0 + eg * 4 + j) * H_ + h0] = o;
  }
}

// ------------- histograms: out-degree (int, by src), in-degree (float, by dst) --
__global__ __launch_bounds__(256) void k_hist(const int* __restrict__ ei,
                                              int* __restrict__ outcnt,
                                              float* __restrict__ degf) {
  int e = blockIdx.x * 256 + threadIdx.x;
  if (e < E_) {
    atomicAdd(&outcnt[ei[e]], 1);
    atomicAdd(&degf[ei[E_ + e]], 1.0f);
  }
}

// ------------- exclusive scan of outcnt -> estart[N+1], cursor ----------------
__global__ __launch_bounds__(1024) void k_scan(const int* __restrict__ outcnt,
                                               int* __restrict__ estart,
                                               int* __restrict__ cursor) {
  __shared__ int part[1024];
  int t = threadIdx.x;
  int base = t * 10;
  int c[10];
  int s = 0;
#pragma unroll
  for (int j = 0; j < 10; ++j) {
    int idx = base + j;
    c[j] = (idx < N_) ? outcnt[idx] : 0;
    s += c[j];
  }
  part[t] = s;
  __syncthreads();
  for (int off = 1; off < 1024; off <<= 1) {
    int v = (t >= off) ? part[t - off] : 0;
    __syncthreads();
    part[t] += v;
    __syncthreads();
  }
  int ex = (t > 0) ? part[t - 1] : 0;
#pragma unroll
  for (int j = 0; j < 10; ++j) {
    int idx = base + j;
    if (idx < N_) { estart[idx] = ex; cursor[idx] = ex; }
    ex += c[j];
  }
  if (t == 1023) estart[N_] = part[1023];
}

// ---------------- scatter: eorder grouped by src ----------------
__global__ __launch_bounds__(256) void k_scatter(const int* __restrict__ ei,
                                                 int* __restrict__ cursor,
                                                 int* __restrict__ eorder) {
  int e = blockIdx.x * 256 + threadIdx.x;
  if (e < E_) {
    int s = ei[e];
    int pos = atomicAdd(&cursor[s], 1);
    eorder[pos] = e;
  }
}

// ---------------- graph start offsets from sorted batch ----------------
__global__ __launch_bounds__(256) void k_gstart(const int* __restrict__ batch,
                                                int* __restrict__ gs) {
  int n = blockIdx.x * 256 + threadIdx.x;
  if (n >= N_) return;
  int b = batch[n];
  if (n == 0) {
    for (int bb = 0; bb <= b; ++bb) gs[bb] = 0;
  } else {
    int pb = batch[n - 1];
    if (pb != b)
      for (int bb = pb + 1; bb <= b; ++bb) gs[bb] = n;
  }
  if (n == N_ - 1) {
    for (int bb = b + 1; bb <= B_; ++bb) gs[bb] = N_;
  }
}

// ------- weight transposes (once per call): GRU 192x64 -> [i][r]; LSTM too ----
__global__ __launch_bounds__(256) void k_transpose(const float* __restrict__ gih,
                                                   const float* __restrict__ ghh,
                                                   const float* __restrict__ lih,
                                                   const float* __restrict__ lhh,
                                                   float* __restrict__ gihT,
                                                   float* __restrict__ ghhT,
                                                   float* __restrict__ lihT,
                                                   float* __restrict__ lhhT) {
  int idx = blockIdx.x * 256 + threadIdx.x;
  if (idx < 192 * 64) {
    int r = idx >> 6, i = idx & 63;
    gihT[i * 192 + r] = gih[idx];
    ghhT[i * 192 + r] = ghh[idx];
  }
  if (idx < 256 * 128) {
    int r = idx >> 7, k = idx & 127;
    lihT[k * 256 + r] = lih[idx];
  }
  if (idx < 256 * 64) {
    int r = idx >> 6, k = idx & 63;
    lhhT[k * 256 + r] = lhh[idx];
  }
}

// ------- nn2_w -> BT[chunk][c=(h_local*64+o)][i] bf16 hi/lo (once per call) ----
// src linear idx = (i*64+o)*128 + h  (coalesced reads, scattered one-time writes)
__global__ __launch_bounds__(256) void k_prep_w(const float* __restrict__ w,
                                                u16* __restrict__ bth,
                                                u16* __restrict__ btl,
                                                int CW) {
  int idx = blockIdx.x * 256 + threadIdx.x;
  if (idx >= 64 * 64 * 128) return;
  int h = idx & 127;
  int io = idx >> 7;
  int o = io & 63;
  int i = io >> 6;
  int chunk = h / CW, hl = h % CW;
  float v = w[idx];
  u16 hh = f2bf(v);
  float r = v - bf2f(hh);
  size_t dst = (size_t)chunk * CW * 4096 + ((size_t)(hl * 64 + o)) * 64 + i;
  bth[dst] = hh;
  btl[dst] = f2bf(r);
}

// ------- per-step activation split: out [N][64] fp32 -> A hi/lo bf16 [NPAD][64] --
__global__ __launch_bounds__(256) void k_split_a(const float* __restrict__ src,
                                                 u16* __restrict__ hi,
                                                 u16* __restrict__ lo) {
  int idx = blockIdx.x * 256 + threadIdx.x;
  if (idx >= NPAD * 64) return;
  float v = (idx < N_ * 64) ? src[idx] : 0.f;
  u16 h = f2bf(v);
  float r = v - bf2f(h);
  hi[idx] = h;
  lo[idx] = f2bf(r);
}

// ---- MFMA V-GEMM (split bf16x3): V[n, h, o] = sum_i A[n,i] * BT[(h*64+o)][i] ----
// Block: 64 n x 256 cols (4 h x 64 o). Wave w: o-range [w*16,w*16+16), 4 h-tiles
// (the 4 h of one V4 float4) x 4 n-tiles. Frags loaded straight from global
// (no LDS). D-layout: row(n) = (l>>4)*4+r, col(o) = l&15  [m89-verified].
// A-frag: a[j] = A[n0+nt*16+(l&15)][(l>>4)*8 + ks*32 + j]  (b128, k-contig).
// B-frag: b[j] = BT[c][ same k ]  with c = (by*4+t)*64 + o0 + (l&15).
// Store: float4 {t=0..3} -> V4[(n*H4Cb + by)*64 + o], 16 lanes = 256B contig.
__global__ __launch_bounds__(256) void k_vgemm_mfma(const u16* __restrict__ Ah,
                                                    const u16* __restrict__ Al,
                                                    const u16* __restrict__ BTh,
                                                    const u16* __restrict__ BTl,
                                                    float* __restrict__ V4,
                                                    int H4Cb) {
  int n0 = blockIdx.x << 6;
  int by = blockIdx.y;            // h4 index within chunk
  int tid = threadIdx.x;
  int w = tid >> 6, l = tid & 63;
  int lr = l & 15, lg = l >> 4;
  int o0 = w << 4;
  int h0 = by << 2;
  f32x4 acc[4][4];
#pragma unroll
  for (int nt = 0; nt < 4; ++nt)
#pragma unroll
    for (int t = 0; t < 4; ++t) acc[nt][t] = (f32x4){0.f, 0.f, 0.f, 0.f};
#pragma unroll
  for (int ks = 0; ks < 2; ++ks) {
    int kk = (lg << 3) + (ks << 5);
    s16x8 ah[4], al[4];
#pragma unroll
    for (int nt = 0; nt < 4; ++nt) {
      size_t ao = (size_t)(n0 + (nt << 4) + lr) * 64 + kk;
      ah[nt] = *(const s16x8*)(Ah + ao);
      al[nt] = *(const s16x8*)(Al + ao);
    }
    s16x8 bh[4], bl[4];
#pragma unroll
    for (int t = 0; t < 4; ++t) {
      size_t bo = (size_t)(((h0 + t) << 6) + o0 + lr) * 64 + kk;
      bh[t] = *(const s16x8*)(BTh + bo);
      bl[t] = *(const s16x8*)(BTl + bo);
    }
#pragma unroll
    for (int nt = 0; nt < 4; ++nt)
#pragma unroll
      for (int t = 0; t < 4; ++t) {
        acc[nt][t] = __builtin_amdgcn_mfma_f32_16x16x32_bf16(ah[nt], bh[t], acc[nt][t], 0, 0, 0);
        acc[nt][t] = __builtin_amdgcn_mfma_f32_16x16x32_bf16(ah[nt], bl[t], acc[nt][t], 0, 0, 0);
        acc[nt][t] = __builtin_amdgcn_mfma_f32_16x16x32_bf16(al[nt], bh[t], acc[nt][t], 0, 0, 0);
      }
  }
  float4* out4 = (float4*)V4;
#pragma unroll
  for (int nt = 0; nt < 4; ++nt)
#pragma unroll
    for (int r = 0; r < 4; ++r) {
      int n = n0 + (nt << 4) + (lg << 2) + r;
      if (n < N_) {
        float4 f;
        f.x = acc[nt][0][r];
        f.y = acc[nt][1][r];
        f.z = acc[nt][2][r];
        f.w = acc[nt][3][r];
        out4[((size_t)n * H4Cb + by) * 64 + o0 + lr] = f;
      }
    }
}

// ---------------- bt[n,o] = sum_i out[n,i]*nn2_b[i*64+o] ----------------
__global__ __launch_bounds__(256) void k_bt(const float* __restrict__ out,
                                            const float* __restrict__ nn2b,
                                            float* __restrict__ bt) {
  __shared__ float os[4][64];
  int n0 = blockIdx.x << 2;
  int tid = threadIdx.x;
  int nl = tid >> 6, o = tid & 63;
  os[nl][o] = out[(size_t)(n0 + nl) * 64 + o];
  __syncthreads();
  float acc = 0.f;
  for (int i = 0; i < 64; ++i) acc += os[nl][i] * nn2b[(i << 6) + o];
  bt[(size_t)(n0 + nl) * 64 + o] = acc;
}

// ---------------- edge contraction, src-grouped, V in registers ----------------
template <int H4C>
__global__ __launch_bounds__(256) void k_edge(const float* __restrict__ V4,
                                              const float* __restrict__ he,
                                              const float* __restrict__ bt,
                                              const int* __restrict__ ei,
                                              const int* __restrict__ estart,
                                              const int* __restrict__ eorder,
                                              float* __restrict__ agg,
                                              int hofs) {
  int wid = threadIdx.x >> 6, lane = threadIdx.x & 63;
  int n = blockIdx.x * 4 + wid;
  if (n >= N_) return;
  int se = estart[n], ee = estart[n + 1];
  if (se == ee) return;
  const float4* vp = (const float4*)V4 + (size_t)n * H4C * 64 + lane;
  float4 v4[H4C];
#pragma unroll
  for (int h4 = 0; h4 < H4C; ++h4) v4[h4] = vp[(size_t)h4 * 64];
  float btv = (hofs == 0) ? bt[(size_t)n * 64 + lane] : 0.f;
  constexpr int CWm1 = 4 * H4C - 1;
  for (int q = se; q < ee; ++q) {
    int eid = eorder[q];
    int dst = ei[E_ + eid];
    const float* hep = &he[(size_t)eid * H_];
    float hh, hh2 = 0.f;
    if (H4C == 32) { hh = hep[lane]; hh2 = hep[64 + lane]; }
    else           { hh = hep[hofs + (lane & CWm1)]; }
    float acc = btv;
#pragma unroll
    for (int h4 = 0; h4 < H4C; ++h4) {
      const float* vv = (const float*)&v4[h4];
#pragma unroll
      for (int c = 0; c < 4; ++c) {
        int hl = h4 * 4 + c;
        float bh = (hl < 64) ? rdlane(hh, hl) : rdlane(hh2, hl - 64);
        acc = fmaf(bh, vv[c], acc);
      }
    }
    atomicAdd(&agg[(size_t)dst * 64 + lane], acc);
  }
}

// ------- node update: m = relu(agg/deg + out@root + cbias); GRU -> nxt ----------
__global__ __launch_bounds__(256) void k_update(const float* __restrict__ agg,
                                                const float* __restrict__ deg,
                                                const float* __restrict__ cur,
                                                const float* __restrict__ root,
                                                const float* __restrict__ cbias,
                                                const float* __restrict__ wihT,
                                                const float* __restrict__ whhT,
                                                const float* __restrict__ bih,
                                                const float* __restrict__ bhh,
                                                float* __restrict__ nxt) {
  __shared__ float outs[32][64];
  __shared__ float ms[32][64];
  int n0 = blockIdx.x << 5;
  int tid = threadIdx.x;
  int o = tid & 63, g = tid >> 6;
#pragma unroll
  for (int k = 0; k < 8; ++k) {
    int idx = tid + (k << 8);
    int nl = idx >> 6, i = idx & 63;
    int n = n0 + nl;
    outs[nl][i] = (n < N_) ? cur[(size_t)n * 64 + i] : 0.f;
  }
  __syncthreads();
  float acc[8];
  float cb = cbias[o];
#pragma unroll
  for (int j = 0; j < 8; ++j) {
    int n = n0 + (g << 3) + j;
    if (n < N_) {
      float dg = deg[n];
      float iv = dg > 0.f ? 1.f / dg : 0.f;
      acc[j] = agg[(size_t)n * 64 + o] * iv + cb;
    } else acc[j] = 0.f;
  }
  for (int i = 0; i < 64; ++i) {
    float r = root[(i << 6) + o];
#pragma unroll
    for (int j = 0; j < 8; ++j) acc[j] = fmaf(outs[(g << 3) + j][i], r, acc[j]);
  }
#pragma unroll
  for (int j = 0; j < 8; ++j) ms[(g << 3) + j][o] = fmaxf(acc[j], 0.f);
  __syncthreads();
  float xr[8], xz[8], xn[8], hr[8], hz[8], hn[8];
  {
    float br = bih[o], bz = bih[64 + o], bn = bih[128 + o];
    float dr = bhh[o], dz = bhh[64 + o], dn = bhh[128 + o];
#pragma unroll
    for (int j = 0; j < 8; ++j) {
      xr[j] = br; xz[j] = bz; xn[j] = bn;
      hr[j] = dr; hz[j] = dz; hn[j] = dn;
    }
  }
  for (int i = 0; i < 64; ++i) {
    const float* wi = &wihT[i * 192];
    const float* vi = &whhT[i * 192];
    float w0 = wi[o], w1 = wi[64 + o], w2 = wi[128 + o];
    float v0 = vi[o], v1 = vi[64 + o], v2 = vi[128 + o];
#pragma unroll
    for (int j = 0; j < 8; ++j) {
      int nl = (g << 3) + j;
      float mi = ms[nl][i], hi = outs[nl][i];
      xr[j] = fmaf(mi, w0, xr[j]);
      xz[j] = fmaf(mi, w1, xz[j]);
      xn[j] = fmaf(mi, w2, xn[j]);
      hr[j] = fmaf(hi, v0, hr[j]);
      hz[j] = fmaf(hi, v1, hz[j]);
      hn[j] = fmaf(hi, v2, hn[j]);
    }
  }
#pragma unroll
  for (int j = 0; j < 8; ++j) {
    int nl = (g << 3) + j;
    int n = n0 + nl;
    if (n < N_) {
      float rg = sigm(xr[j] + hr[j]);
      float zg = sigm(xz[j] + hz[j]);
      float ng = tanhf(xn[j] + rg * hn[j]);
      nxt[(size_t)n * 64 + o] = (1.f - zg) * ng + zg * outs[nl][o];
    }
  }
}

// ------- Set2Set fused step: LSTM cell + attention pooling (+ final MLP) -------
__global__ __launch_bounds__(256) void k_s2s(const float* __restrict__ out,
                                             const int* __restrict__ gs,
                                             float* __restrict__ qstar,
                                             float* __restrict__ hs,
                                             float* __restrict__ cs,
                                             const float* __restrict__ lihT,
                                             const float* __restrict__ lhhT,
                                             const float* __restrict__ bih,
                                             const float* __restrict__ bhh,
                                             const float* __restrict__ w1,
                                             const float* __restrict__ b1,
                                             const float* __restrict__ w2,
                                             const float* __restrict__ b2,
                                             float* __restrict__ y, int dofinal) {
  int b = blockIdx.x, tid = threadIdx.x;
  __shared__ float qs[128];
  __shared__ float hss[64];
  __shared__ float gsh[256];
  __shared__ float qv[64];
  __shared__ float rv[64];
  __shared__ float wred[4];
  __shared__ float rred[4][64];
  if (tid < 128) qs[tid] = qstar[b * 128 + tid];
  else if (tid < 192) hss[tid - 128] = hs[b * 64 + (tid - 128)];
  __syncthreads();
  {
    int r = tid;
    float acc = bih[r] + bhh[r];
    for (int k = 0; k < 128; ++k) acc += qs[k] * lihT[k * 256 + r];
    for (int k = 0; k < 64; ++k) acc += hss[k] * lhhT[k * 256 + r];
    gsh[r] = acc;
  }
  __syncthreads();
  if (tid < 64) {
    float ig = sigm(gsh[tid]), fg = sigm(gsh[64 + tid]);
    float gg = tanhf(gsh[128 + tid]), og = sigm(gsh[192 + tid]);
    float c = fg * cs[b * 64 + tid] + ig * gg;
    cs[b * 64 + tid] = c;
    float hv = og * tanhf(c);
    hs[b * 64 + tid] = hv;
    qv[tid] = hv;
  }
  __syncthreads();
  int wid = tid >> 6, l = tid & 63;
  int s = gs[b], e_ = gs[b + 1];
  float wmax = -3.4e38f;
  for (int n = s + wid; n < e_; n += 4) {
    float p = out[(size_t)n * 64 + l] * qv[l];
#pragma unroll
    for (int off = 32; off; off >>= 1) p += __shfl_xor(p, off);
    wmax = fmaxf(wmax, p);
  }
  if (l == 0) wred[wid] = wmax;
  __syncthreads();
  float gmax = fmaxf(fmaxf(wred[0], wred[1]), fmaxf(wred[2], wred[3]));
  __syncthreads();
  float dacc = 0.f, racc = 0.f;
  for (int n = s + wid; n < e_; n += 4) {
    float p = out[(size_t)n * 64 + l] * qv[l];
#pragma unroll
    for (int off = 32; off; off >>= 1) p += __shfl_xor(p, off);
    float ee = __expf(p - gmax);
    dacc += ee;
    racc += ee * out[(size_t)n * 64 + l];
  }
  rred[wid][l] = racc;
  if (l == 0) wred[wid] = dacc;
  __syncthreads();
  if (wid == 0) {
    float denom = wred[0] + wred[1] + wred[2] + wred[3];
    float r = (rred[0][l] + rred[1][l] + rred[2][l] + rred[3][l]) /
              fmaxf(denom, 1e-16f);
    rv[l] = r;
    qstar[b * 128 + l] = qv[l];
    qstar[b * 128 + 64 + l] = r;
  }
  if (dofinal) {
    __syncthreads();
    if (tid < 64) {
      float acc = b1[tid];
      for (int k = 0; k < 64; ++k) acc += qv[k] * w1[tid * 128 + k];
      for (int k = 0; k < 64; ++k) acc += rv[k] * w1[tid * 128 + 64 + k];
      float t1 = fmaxf(acc, 0.f) * w2[tid];
#pragma unroll
      for (int off = 32; off; off >>= 1) t1 += __shfl_xor(t1, off);
      if (tid == 0) y[b] = t1 + b2[0];
    }
  }
}

extern "C" void kernel_launch(void* const* d_in, const int* in_sizes, int n_in,
                              void* d_out, int out_size, void* d_ws, size_t ws_size,
                              hipStream_t stream) {
  const float* x        = (const float*)d_in[0];
  const float* ea       = (const float*)d_in[1];
  const float* lin0_w   = (const float*)d_in[2];
  const float* lin0_b   = (const float*)d_in[3];
  const float* nn1_w    = (const float*)d_in[4];
  const float* nn1_b    = (const float*)d_in[5];
  const float* nn2_w    = (const float*)d_in[6];
  const float* nn2_b    = (const float*)d_in[7];
  const float* root     = (const float*)d_in[8];
  const float* cbias    = (const float*)d_in[9];
  const float* gru_wih  = (const float*)d_in[10];
  const float* gru_whh  = (const float*)d_in[11];
  const float* gru_bih  = (const float*)d_in[12];
  const float* gru_bhh  = (const float*)d_in[13];
  const float* lstm_wih = (const float*)d_in[14];
  const float* lstm_whh = (const float*)d_in[15];
  const float* lstm_bih = (const float*)d_in[16];
  const float* lstm_bhh = (const float*)d_in[17];
  const float* lin1_w   = (const float*)d_in[18];
  const float* lin1_b   = (const float*)d_in[19];
  const float* lin2_w   = (const float*)d_in[20];
  const float* lin2_b   = (const float*)d_in[21];
  const int*   ei       = (const int*)d_in[22];
  const int*   batch    = (const int*)d_in[23];
  float* yout = (float*)d_out;
  (void)n_in; (void)in_sizes; (void)out_size;

  // ---- workspace carve-up (256B aligned); zero-group first (single memset) ----
  size_t off = 0;
  auto carve = [&](size_t bytes) -> void* {
    void* p = (char*)d_ws + off;
    off = (off + bytes + 255) & ~(size_t)255;
    return p;
  };
  float* deg    = (float*)carve((size_t)N_ * 4);
  int*   outcnt = (int*)carve((size_t)N_ * 4);
  float* qstar  = (float*)carve((size_t)B_ * 128 * 4);
  float* hs     = (float*)carve((size_t)B_ * 64 * 4);
  float* cs     = (float*)carve((size_t)B_ * 64 * 4);
  size_t zero_span = off;
  float* out_a  = (float*)carve((size_t)N_ * DIM_ * 4);
  float* out_b  = (float*)carve((size_t)N_ * DIM_ * 4);
  float* bt     = (float*)carve((size_t)N_ * DIM_ * 4);
  float* agg    = (float*)carve((size_t)N_ * DIM_ * 4);
  int*   estart = (int*)carve((size_t)(N_ + 1) * 4);
  int*   cursor = (int*)carve((size_t)N_ * 4);
  int*   eorder = (int*)carve((size_t)E_ * 4);
  int*   gs     = (int*)carve((size_t)(B_ + 1) * 4);
  float* gihT   = (float*)carve((size_t)192 * 64 * 4);
  float* ghhT   = (float*)carve((size_t)192 * 64 * 4);
  float* lihT   = (float*)carve((size_t)256 * 128 * 4);
  float* lhhT   = (float*)carve((size_t)256 * 64 * 4);
  u16*   Ah     = (u16*)carve((size_t)NPAD * 64 * 2);
  u16*   Al     = (u16*)carve((size_t)NPAD * 64 * 2);
  u16*   BTh    = (u16*)carve((size_t)128 * 4096 * 2);
  u16*   BTl    = (u16*)carve((size_t)128 * 4096 * 2);
  float* he     = (float*)carve((size_t)E_ * H_ * 4);
  size_t common = off;
  // ---- h-chunk width: cap at 64 so V (164 MB) + he (51 MB) stay L3-resident ----
  int CW = 8;
  {
    const int cws[4] = {64, 32, 16, 8};
    for (int i = 0; i < 4; ++i) {
      size_t vb = (size_t)N_ * cws[i] * 64 * 4;
      if (common + vb <= ws_size) { CW = cws[i]; break; }
    }
  }
  float* V4 = (float*)carve((size_t)N_ * CW * 64 * 4);
  int nchunks = 128 / CW;
  int H4Cb = CW / 4;

  // ---- init ----
  hipMemsetAsync(d_ws, 0, zero_span, stream);

  k_lin0<<<N_ / 4, 256, 0, stream>>>(x, lin0_w, lin0_b, out_a);
  k_he<<<E_ / 32, 256, 0, stream>>>(ea, nn1_w, nn1_b, he);
  k_hist<<<(E_ + 255) / 256, 256, 0, stream>>>(ei, outcnt, deg);
  k_scan<<<1, 1024, 0, stream>>>(outcnt, estart, cursor);
  k_scatter<<<(E_ + 255) / 256, 256, 0, stream>>>(ei, cursor, eorder);
  k_gstart<<<(N_ + 255) / 256, 256, 0, stream>>>(batch, gs);
  k_transpose<<<128, 256, 0, stream>>>(gru_wih, gru_whh, lstm_wih, lstm_whh,
                                       gihT, ghhT, lihT, lhhT);
  k_prep_w<<<2048, 256, 0, stream>>>(nn2_w, BTh, BTl, CW);

  // ---- 2 conv+GRU steps ----
  float* cur = out_a;
  float* nxt = out_b;
  int egrid = (N_ + 3) / 4;
  int nblk = NPAD / 64;  // 157
  for (int t = 0; t < 2; ++t) {
    hipMemsetAsync(agg, 0, (size_t)N_ * DIM_ * 4, stream);
    k_bt<<<N_ / 4, 256, 0, stream>>>(cur, nn2_b, bt);
    k_split_a<<<(NPAD * 64 + 255) / 256, 256, 0, stream>>>(cur, Ah, Al);
    for (int chunk = 0; chunk < nchunks; ++chunk) {
      int h_base = chunk * CW;
      size_t boff = (size_t)chunk * CW * 4096;
      dim3 vg(nblk, H4Cb);
      k_vgemm_mfma<<<vg, 256, 0, stream>>>(Ah, Al, BTh + boff, BTl + boff, V4, H4Cb);
      switch (CW) {
        case 64:  k_edge<16><<<egrid, 256, 0, stream>>>(V4, he, bt, ei, estart, eorder, agg, h_base); break;
        case 32:  k_edge<8><<<egrid, 256, 0, stream>>>(V4, he, bt, ei, estart, eorder, agg, h_base); break;
        case 16:  k_edge<4><<<egrid, 256, 0, stream>>>(V4, he, bt, ei, estart, eorder, agg, h_base); break;
        default:  k_edge<2><<<egrid, 256, 0, stream>>>(V4, he, bt, ei, estart, eorder, agg, h_base); break;
      }
    }
    k_update<<<(N_ + 31) / 32, 256, 0, stream>>>(agg, deg, cur, root, cbias,
                                                 gihT, ghhT, gru_bih, gru_bhh, nxt);
    float* tmp = cur; cur = nxt; nxt = tmp;
  }

  // ---- Set2Set (2 fused steps; final MLP folded into step 2) ----
  k_s2s<<<B_, 256, 0, stream>>>(cur, gs, qstar, hs, cs, lihT, lhhT,
                                lstm_bih, lstm_bhh, lin1_w, lin1_b, lin2_w,
                                lin2_b, yout, 0);
  k_s2s<<<B_, 256, 0, stream>>>(cur, gs, qstar, hs, cs, lihT, lhhT,
                                lstm_bih, lstm_bhh, lin1_w, lin1_b, lin2_w,
                                lin2_b, yout, 1);
}

// Round 9
// 792.068 us; speedup vs baseline: 1.2680x; 1.0325x over previous
//
#include <hip/hip_runtime.h>
#include <hip/hip_bf16.h>

// Problem sizes (fixed)
#define N_   10000
#define E_   100000
#define B_   64
#define DIM_ 64
#define NF_  92
#define EF_  50
#define H_   128
#define NPAD 10048   // 157 * 64, padded node count for MFMA tiles

typedef unsigned int u32;
typedef unsigned short u16;
typedef __attribute__((ext_vector_type(8))) short s16x8;   // 8 bf16 (4 VGPRs)
typedef __attribute__((ext_vector_type(4))) float f32x4;

__device__ __forceinline__ float sigm(float x) { return 1.f / (1.f + __expf(-x)); }
__device__ __forceinline__ float rdlane(float v, int l) {
  return __uint_as_float(__builtin_amdgcn_readlane(__float_as_uint(v), l));
}
__device__ __forceinline__ float bf2f(u16 u) {
  return __uint_as_float(((u32)u) << 16);
}
__device__ __forceinline__ u16 f2bf(float f) {
  u32 u = __float_as_uint(f);
  u32 r = (u + 0x7FFFu + ((u >> 16) & 1u)) >> 16;
  return (u16)r;
}

// ---------------- lin0: out = relu(x @ lin0_w.T + b)  [N, DIM] ----------------
__global__ __launch_bounds__(256) void k_lin0(const float* __restrict__ x,
                                              const float* __restrict__ w,
                                              const float* __restrict__ b,
                                              float* __restrict__ out) {
  __shared__ float xs[4][NF_];
  __shared__ float w_s[DIM_][93];
  int n0 = blockIdx.x << 2;
  int tid = threadIdx.x;
  for (int k = tid; k < 4 * NF_; k += 256) {
    int nl = k / NF_, f = k % NF_;
    xs[nl][f] = x[(size_t)(n0 + nl) * NF_ + f];
  }
  for (int g = tid; g < DIM_ * NF_; g += 256) {
    int d = g / NF_, f = g % NF_;
    w_s[d][f] = w[g];
  }
  __syncthreads();
  int nl = tid >> 6, d = tid & 63;
  float acc = b[d];
  for (int f = 0; f < NF_; ++f) acc += xs[nl][f] * w_s[d][f];
  out[(size_t)(n0 + nl) * DIM_ + d] = fmaxf(acc, 0.f);
}

// ------------- histograms: out-degree (int, by src), in-degree (float, by dst) --
__global__ __launch_bounds__(256) void k_hist(const int* __restrict__ ei,
                                              int* __restrict__ outcnt,
                                              float* __restrict__ degf) {
  int e = blockIdx.x * 256 + threadIdx.x;
  if (e < E_) {
    atomicAdd(&outcnt[ei[e]], 1);
    atomicAdd(&degf[ei[E_ + e]], 1.0f);
  }
}

// ------------- exclusive scan of outcnt -> estart[N+1], cursor ----------------
__global__ __launch_bounds__(1024) void k_scan(const int* __restrict__ outcnt,
                                               int* __restrict__ estart,
                                               int* __restrict__ cursor) {
  __shared__ int part[1024];
  int t = threadIdx.x;
  int base = t * 10;
  int c[10];
  int s = 0;
#pragma unroll
  for (int j = 0; j < 10; ++j) {
    int idx = base + j;
    c[j] = (idx < N_) ? outcnt[idx] : 0;
    s += c[j];
  }
  part[t] = s;
  __syncthreads();
  for (int off = 1; off < 1024; off <<= 1) {
    int v = (t >= off) ? part[t - off] : 0;
    __syncthreads();
    part[t] += v;
    __syncthreads();
  }
  int ex = (t > 0) ? part[t - 1] : 0;
#pragma unroll
  for (int j = 0; j < 10; ++j) {
    int idx = base + j;
    if (idx < N_) { estart[idx] = ex; cursor[idx] = ex; }
    ex += c[j];
  }
  if (t == 1023) estart[N_] = part[1023];
}

// ------- scatter: epos[e] = slot of edge e in src-sorted order; dst_s[slot] ----
__global__ __launch_bounds__(256) void k_scatter(const int* __restrict__ ei,
                                                 int* __restrict__ cursor,
                                                 int* __restrict__ epos,
                                                 int* __restrict__ dst_s) {
  int e = blockIdx.x * 256 + threadIdx.x;
  if (e < E_) {
    int s = ei[e];
    int pos = atomicAdd(&cursor[s], 1);
    epos[e] = pos;
    dst_s[pos] = ei[E_ + e];
  }
}

// ---- he = relu(edge_attr @ nn1_w.T + b), written SRC-SORTED + chunk-major ----
// he_s layout: [chunk][q][CW] where q = epos[e], chunk = h / CW.
__global__ __launch_bounds__(256) void k_he(const float* __restrict__ ea,
                                            const float* __restrict__ w,
                                            const float* __restrict__ b,
                                            float* __restrict__ he_s,
                                            const int* __restrict__ epos,
                                            int lcw) {
  __shared__ float wt[EF_][132];  // wt[f][h]
  __shared__ float es[32][52];    // es[e][f]
  int e0 = blockIdx.x * 32, t = threadIdx.x;
  for (int g = t; g < H_ * EF_; g += 256) {
    int h = g / EF_, f = g % EF_;
    wt[f][h] = w[g];
  }
  for (int g = t; g < 32 * EF_; g += 256) {
    int e = g / EF_, f = g % EF_;
    es[e][f] = ea[(size_t)(e0 + e) * EF_ + f];
  }
  __syncthreads();
  int h0 = (t & 31) << 2, eg = t >> 5;  // eg in [0,8): 4 edges each
  float acc[4][4];
#pragma unroll
  for (int j = 0; j < 4; ++j)
#pragma unroll
    for (int c = 0; c < 4; ++c) acc[j][c] = b[h0 + c];
  for (int f = 0; f < EF_; ++f) {
    float4 wv = *(const float4*)&wt[f][h0];
    const float* wp = (const float*)&wv;
#pragma unroll
    for (int j = 0; j < 4; ++j) {
      float ev = es[eg * 4 + j][f];
#pragma unroll
      for (int c = 0; c < 4; ++c) acc[j][c] = fmaf(ev, wp[c], acc[j][c]);
    }
  }
  int cwm1 = (1 << lcw) - 1;
#pragma unroll
  for (int j = 0; j < 4; ++j) {
    float4 o;
    o.x = fmaxf(acc[j][0], 0.f); o.y = fmaxf(acc[j][1], 0.f);
    o.z = fmaxf(acc[j][2], 0.f); o.w = fmaxf(acc[j][3], 0.f);
    int e = e0 + eg * 4 + j;
    int pos = epos[e];
    int chunk = h0 >> lcw;
    int hl = h0 & cwm1;
    *(float4*)&he_s[(((size_t)chunk * E_ + pos) << lcw) + hl] = o;
  }
}

// ---------------- graph start offsets from sorted batch ----------------
__global__ __launch_bounds__(256) void k_gstart(const int* __restrict__ batch,
                                                int* __restrict__ gs) {
  int n = blockIdx.x * 256 + threadIdx.x;
  if (n >= N_) return;
  int b = batch[n];
  if (n == 0) {
    for (int bb = 0; bb <= b; ++bb) gs[bb] = 0;
  } else {
    int pb = batch[n - 1];
    if (pb != b)
      for (int bb = pb + 1; bb <= b; ++bb) gs[bb] = n;
  }
  if (n == N_ - 1) {
    for (int bb = b + 1; bb <= B_; ++bb) gs[bb] = N_;
  }
}

// ------- weight transposes (once per call): GRU 192x64 -> [i][r]; LSTM too ----
__global__ __launch_bounds__(256) void k_transpose(const float* __restrict__ gih,
                                                   const float* __restrict__ ghh,
                                                   const float* __restrict__ lih,
                                                   const float* __restrict__ lhh,
                                                   float* __restrict__ gihT,
                                                   float* __restrict__ ghhT,
                                                   float* __restrict__ lihT,
                                                   float* __restrict__ lhhT) {
  int idx = blockIdx.x * 256 + threadIdx.x;
  if (idx < 192 * 64) {
    int r = idx >> 6, i = idx & 63;
    gihT[i * 192 + r] = gih[idx];
    ghhT[i * 192 + r] = ghh[idx];
  }
  if (idx < 256 * 128) {
    int r = idx >> 7, k = idx & 127;
    lihT[k * 256 + r] = lih[idx];
  }
  if (idx < 256 * 64) {
    int r = idx >> 6, k = idx & 63;
    lhhT[k * 256 + r] = lhh[idx];
  }
}

// ------- nn2_w -> BT[chunk][c=(h_local*64+o)][i] bf16 hi/lo (once per call) ----
__global__ __launch_bounds__(256) void k_prep_w(const float* __restrict__ w,
                                                u16* __restrict__ bth,
                                                u16* __restrict__ btl,
                                                int CW) {
  int idx = blockIdx.x * 256 + threadIdx.x;
  if (idx >= 64 * 64 * 128) return;
  int h = idx & 127;
  int io = idx >> 7;
  int o = io & 63;
  int i = io >> 6;
  int chunk = h / CW, hl = h % CW;
  float v = w[idx];
  u16 hh = f2bf(v);
  float r = v - bf2f(hh);
  size_t dst = (size_t)chunk * CW * 4096 + ((size_t)(hl * 64 + o)) * 64 + i;
  bth[dst] = hh;
  btl[dst] = f2bf(r);
}

// ------- per-step activation split: out [N][64] fp32 -> A hi/lo bf16 [NPAD][64] --
__global__ __launch_bounds__(256) void k_split_a(const float* __restrict__ src,
                                                 u16* __restrict__ hi,
                                                 u16* __restrict__ lo) {
  int idx = blockIdx.x * 256 + threadIdx.x;
  if (idx >= NPAD * 64) return;
  float v = (idx < N_ * 64) ? src[idx] : 0.f;
  u16 h = f2bf(v);
  float r = v - bf2f(h);
  hi[idx] = h;
  lo[idx] = f2bf(r);
}

// ---- MFMA V-GEMM (split bf16x3): V[n, h, o] = sum_i A[n,i] * BT[(h*64+o)][i] ----
__global__ __launch_bounds__(256) void k_vgemm_mfma(const u16* __restrict__ Ah,
                                                    const u16* __restrict__ Al,
                                                    const u16* __restrict__ BTh,
                                                    const u16* __restrict__ BTl,
                                                    float* __restrict__ V4,
                                                    int H4Cb) {
  int n0 = blockIdx.x << 6;
  int by = blockIdx.y;            // h4 index within chunk
  int tid = threadIdx.x;
  int w = tid >> 6, l = tid & 63;
  int lr = l & 15, lg = l >> 4;
  int o0 = w << 4;
  int h0 = by << 2;
  f32x4 acc[4][4];
#pragma unroll
  for (int nt = 0; nt < 4; ++nt)
#pragma unroll
    for (int t = 0; t < 4; ++t) acc[nt][t] = (f32x4){0.f, 0.f, 0.f, 0.f};
#pragma unroll
  for (int ks = 0; ks < 2; ++ks) {
    int kk = (lg << 3) + (ks << 5);
    s16x8 ah[4], al[4];
#pragma unroll
    for (int nt = 0; nt < 4; ++nt) {
      size_t ao = (size_t)(n0 + (nt << 4) + lr) * 64 + kk;
      ah[nt] = *(const s16x8*)(Ah + ao);
      al[nt] = *(const s16x8*)(Al + ao);
    }
    s16x8 bh[4], bl[4];
#pragma unroll
    for (int t = 0; t < 4; ++t) {
      size_t bo = (size_t)(((h0 + t) << 6) + o0 + lr) * 64 + kk;
      bh[t] = *(const s16x8*)(BTh + bo);
      bl[t] = *(const s16x8*)(BTl + bo);
    }
#pragma unroll
    for (int nt = 0; nt < 4; ++nt)
#pragma unroll
      for (int t = 0; t < 4; ++t) {
        acc[nt][t] = __builtin_amdgcn_mfma_f32_16x16x32_bf16(ah[nt], bh[t], acc[nt][t], 0, 0, 0);
        acc[nt][t] = __builtin_amdgcn_mfma_f32_16x16x32_bf16(ah[nt], bl[t], acc[nt][t], 0, 0, 0);
        acc[nt][t] = __builtin_amdgcn_mfma_f32_16x16x32_bf16(al[nt], bh[t], acc[nt][t], 0, 0, 0);
      }
  }
  float4* out4 = (float4*)V4;
#pragma unroll
  for (int nt = 0; nt < 4; ++nt)
#pragma unroll
    for (int r = 0; r < 4; ++r) {
      int n = n0 + (nt << 4) + (lg << 2) + r;
      if (n < N_) {
        float4 f;
        f.x = acc[nt][0][r];
        f.y = acc[nt][1][r];
        f.z = acc[nt][2][r];
        f.w = acc[nt][3][r];
        out4[((size_t)n * H4Cb + by) * 64 + o0 + lr] = f;
      }
    }
}

// ---------------- bt[n,o] = sum_i out[n,i]*nn2_b[i*64+o] ----------------
__global__ __launch_bounds__(256) void k_bt(const float* __restrict__ out,
                                            const float* __restrict__ nn2b,
                                            float* __restrict__ bt) {
  __shared__ float os[4][64];
  int n0 = blockIdx.x << 2;
  int tid = threadIdx.x;
  int nl = tid >> 6, o = tid & 63;
  os[nl][o] = out[(size_t)(n0 + nl) * 64 + o];
  __syncthreads();
  float acc = 0.f;
  for (int i = 0; i < 64; ++i) acc += os[nl][i] * nn2b[(i << 6) + o];
  bt[(size_t)(n0 + nl) * 64 + o] = acc;
}

// ------- edge contraction: V pinned in VGPRs, he/dst as sorted streams --------
// wave = one src node n; lane = o. he row for slot q: heq[q*CW + (lane&CW-1)];
// rdlane broadcasts each h across the wave. 1-edge lookahead prefetch.
template <int H4C>
__global__ __launch_bounds__(256) void k_edge(const float* __restrict__ V4,
                                              const float* __restrict__ heq,
                                              const float* __restrict__ bt,
                                              const int* __restrict__ dst_s,
                                              const int* __restrict__ estart,
                                              float* __restrict__ agg,
                                              int addbt) {
  constexpr int CW = 4 * H4C;
  int wid = threadIdx.x >> 6, lane = threadIdx.x & 63;
  int n = blockIdx.x * 4 + wid;
  if (n >= N_) return;
  int se = estart[n], ee = estart[n + 1];
  if (se == ee) return;
  const float4* vp = (const float4*)V4 + (size_t)n * H4C * 64 + lane;
  float4 v4[H4C];
#pragma unroll
  for (int h4 = 0; h4 < H4C; ++h4) v4[h4] = vp[(size_t)h4 * 64];
  // Pin V in VGPRs: opaque to the compiler -> cannot re-load from memory.
#pragma unroll
  for (int h4 = 0; h4 < H4C; ++h4)
    asm volatile("" : "+v"(v4[h4].x), "+v"(v4[h4].y), "+v"(v4[h4].z), "+v"(v4[h4].w));
  float btv = addbt ? bt[(size_t)n * 64 + lane] : 0.f;
  int hl = lane & (CW - 1);
  float hh = heq[(size_t)se * CW + hl];
  int dst = dst_s[se];
  for (int q = se; q < ee; ++q) {
    float hc = hh;
    int dc = dst;
    if (q + 1 < ee) {
      hh = heq[(size_t)(q + 1) * CW + hl];
      dst = dst_s[q + 1];
    }
    float acc = btv;
#pragma unroll
    for (int h4 = 0; h4 < H4C; ++h4) {
      const float* vv = &v4[h4].x;
#pragma unroll
      for (int c = 0; c < 4; ++c) {
        float bh = rdlane(hc, h4 * 4 + c);
        acc = fmaf(bh, vv[c], acc);
      }
    }
    atomicAdd(&agg[(size_t)dc * 64 + lane], acc);
  }
}

// ------- node update: m = relu(agg/deg + out@root + cbias); GRU -> nxt ----------
__global__ __launch_bounds__(256) void k_update(const float* __restrict__ agg,
                                                const float* __restrict__ deg,
                                                const float* __restrict__ cur,
                                                const float* __restrict__ root,
                                                const float* __restrict__ cbias,
                                                const float* __restrict__ wihT,
                                                const float* __restrict__ whhT,
                                                const float* __restrict__ bih,
                                                const float* __restrict__ bhh,
                                                float* __restrict__ nxt) {
  __shared__ float outs[32][64];
  __shared__ float ms[32][64];
  int n0 = blockIdx.x << 5;
  int tid = threadIdx.x;
  int o = tid & 63, g = tid >> 6;
#pragma unroll
  for (int k = 0; k < 8; ++k) {
    int idx = tid + (k << 8);
    int nl = idx >> 6, i = idx & 63;
    int n = n0 + nl;
    outs[nl][i] = (n < N_) ? cur[(size_t)n * 64 + i] : 0.f;
  }
  __syncthreads();
  float acc[8];
  float cb = cbias[o];
#pragma unroll
  for (int j = 0; j < 8; ++j) {
    int n = n0 + (g << 3) + j;
    if (n < N_) {
      float dg = deg[n];
      float iv = dg > 0.f ? 1.f / dg : 0.f;
      acc[j] = agg[(size_t)n * 64 + o] * iv + cb;
    } else acc[j] = 0.f;
  }
  for (int i = 0; i < 64; ++i) {
    float r = root[(i << 6) + o];
#pragma unroll
    for (int j = 0; j < 8; ++j) acc[j] = fmaf(outs[(g << 3) + j][i], r, acc[j]);
  }
#pragma unroll
  for (int j = 0; j < 8; ++j) ms[(g << 3) + j][o] = fmaxf(acc[j], 0.f);
  __syncthreads();
  float xr[8], xz[8], xn[8], hr[8], hz[8], hn[8];
  {
    float br = bih[o], bz = bih[64 + o], bn = bih[128 + o];
    float dr = bhh[o], dz = bhh[64 + o], dn = bhh[128 + o];
#pragma unroll
    for (int j = 0; j < 8; ++j) {
      xr[j] = br; xz[j] = bz; xn[j] = bn;
      hr[j] = dr; hz[j] = dz; hn[j] = dn;
    }
  }
  for (int i = 0; i < 64; ++i) {
    const float* wi = &wihT[i * 192];
    const float* vi = &whhT[i * 192];
    float w0 = wi[o], w1 = wi[64 + o], w2 = wi[128 + o];
    float v0 = vi[o], v1 = vi[64 + o], v2 = vi[128 + o];
#pragma unroll
    for (int j = 0; j < 8; ++j) {
      int nl = (g << 3) + j;
      float mi = ms[nl][i], hi = outs[nl][i];
      xr[j] = fmaf(mi, w0, xr[j]);
      xz[j] = fmaf(mi, w1, xz[j]);
      xn[j] = fmaf(mi, w2, xn[j]);
      hr[j] = fmaf(hi, v0, hr[j]);
      hz[j] = fmaf(hi, v1, hz[j]);
      hn[j] = fmaf(hi, v2, hn[j]);
    }
  }
#pragma unroll
  for (int j = 0; j < 8; ++j) {
    int nl = (g << 3) + j;
    int n = n0 + nl;
    if (n < N_) {
      float rg = sigm(xr[j] + hr[j]);
      float zg = sigm(xz[j] + hz[j]);
      float ng = tanhf(xn[j] + rg * hn[j]);
      nxt[(size_t)n * 64 + o] = (1.f - zg) * ng + zg * outs[nl][o];
    }
  }
}

// ------- Set2Set fused step: LSTM cell + attention pooling (+ final MLP) -------
__global__ __launch_bounds__(256) void k_s2s(const float* __restrict__ out,
                                             const int* __restrict__ gs,
                                             float* __restrict__ qstar,
                                             float* __restrict__ hs,
                                             float* __restrict__ cs,
                                             const float* __restrict__ lihT,
                                             const float* __restrict__ lhhT,
                                             const float* __restrict__ bih,
                                             const float* __restrict__ bhh,
                                             const float* __restrict__ w1,
                                             const float* __restrict__ b1,
                                             const float* __restrict__ w2,
                                             const float* __restrict__ b2,
                                             float* __restrict__ y, int dofinal) {
  int b = blockIdx.x, tid = threadIdx.x;
  __shared__ float qs[128];
  __shared__ float hss[64];
  __shared__ float gsh[256];
  __shared__ float qv[64];
  __shared__ float rv[64];
  __shared__ float wred[4];
  __shared__ float rred[4][64];
  if (tid < 128) qs[tid] = qstar[b * 128 + tid];
  else if (tid < 192) hss[tid - 128] = hs[b * 64 + (tid - 128)];
  __syncthreads();
  {
    int r = tid;
    float acc = bih[r] + bhh[r];
    for (int k = 0; k < 128; ++k) acc += qs[k] * lihT[k * 256 + r];
    for (int k = 0; k < 64; ++k) acc += hss[k] * lhhT[k * 256 + r];
    gsh[r] = acc;
  }
  __syncthreads();
  if (tid < 64) {
    float ig = sigm(gsh[tid]), fg = sigm(gsh[64 + tid]);
    float gg = tanhf(gsh[128 + tid]), og = sigm(gsh[192 + tid]);
    float c = fg * cs[b * 64 + tid] + ig * gg;
    cs[b * 64 + tid] = c;
    float hv = og * tanhf(c);
    hs[b * 64 + tid] = hv;
    qv[tid] = hv;
  }
  __syncthreads();
  int wid = tid >> 6, l = tid & 63;
  int s = gs[b], e_ = gs[b + 1];
  float wmax = -3.4e38f;
  for (int n = s + wid; n < e_; n += 4) {
    float p = out[(size_t)n * 64 + l] * qv[l];
#pragma unroll
    for (int off = 32; off; off >>= 1) p += __shfl_xor(p, off);
    wmax = fmaxf(wmax, p);
  }
  if (l == 0) wred[wid] = wmax;
  __syncthreads();
  float gmax = fmaxf(fmaxf(wred[0], wred[1]), fmaxf(wred[2], wred[3]));
  __syncthreads();
  float dacc = 0.f, racc = 0.f;
  for (int n = s + wid; n < e_; n += 4) {
    float p = out[(size_t)n * 64 + l] * qv[l];
#pragma unroll
    for (int off = 32; off; off >>= 1) p += __shfl_xor(p, off);
    float ee = __expf(p - gmax);
    dacc += ee;
    racc += ee * out[(size_t)n * 64 + l];
  }
  rred[wid][l] = racc;
  if (l == 0) wred[wid] = dacc;
  __syncthreads();
  if (wid == 0) {
    float denom = wred[0] + wred[1] + wred[2] + wred[3];
    float r = (rred[0][l] + rred[1][l] + rred[2][l] + rred[3][l]) /
              fmaxf(denom, 1e-16f);
    rv[l] = r;
    qstar[b * 128 + l] = qv[l];
    qstar[b * 128 + 64 + l] = r;
  }
  if (dofinal) {
    __syncthreads();
    if (tid < 64) {
      float acc = b1[tid];
      for (int k = 0; k < 64; ++k) acc += qv[k] * w1[tid * 128 + k];
      for (int k = 0; k < 64; ++k) acc += rv[k] * w1[tid * 128 + 64 + k];
      float t1 = fmaxf(acc, 0.f) * w2[tid];
#pragma unroll
      for (int off = 32; off; off >>= 1) t1 += __shfl_xor(t1, off);
      if (tid == 0) y[b] = t1 + b2[0];
    }
  }
}

extern "C" void kernel_launch(void* const* d_in, const int* in_sizes, int n_in,
                              void* d_out, int out_size, void* d_ws, size_t ws_size,
                              hipStream_t stream) {
  const float* x        = (const float*)d_in[0];
  const float* ea       = (const float*)d_in[1];
  const float* lin0_w   = (const float*)d_in[2];
  const float* lin0_b   = (const float*)d_in[3];
  const float* nn1_w    = (const float*)d_in[4];
  const float* nn1_b    = (const float*)d_in[5];
  const float* nn2_w    = (const float*)d_in[6];
  const float* nn2_b    = (const float*)d_in[7];
  const float* root     = (const float*)d_in[8];
  const float* cbias    = (const float*)d_in[9];
  const float* gru_wih  = (const float*)d_in[10];
  const float* gru_whh  = (const float*)d_in[11];
  const float* gru_bih  = (const float*)d_in[12];
  const float* gru_bhh  = (const float*)d_in[13];
  const float* lstm_wih = (const float*)d_in[14];
  const float* lstm_whh = (const float*)d_in[15];
  const float* lstm_bih = (const float*)d_in[16];
  const float* lstm_bhh = (const float*)d_in[17];
  const float* lin1_w   = (const float*)d_in[18];
  const float* lin1_b   = (const float*)d_in[19];
  const float* lin2_w   = (const float*)d_in[20];
  const float* lin2_b   = (const float*)d_in[21];
  const int*   ei       = (const int*)d_in[22];
  const int*   batch    = (const int*)d_in[23];
  float* yout = (float*)d_out;
  (void)n_in; (void)in_sizes; (void)out_size;

  // ---- workspace carve-up (256B aligned); zero-group first (single memset) ----
  size_t off = 0;
  auto carve = [&](size_t bytes) -> void* {
    void* p = (char*)d_ws + off;
    off = (off + bytes + 255) & ~(size_t)255;
    return p;
  };
  float* deg    = (float*)carve((size_t)N_ * 4);
  int*   outcnt = (int*)carve((size_t)N_ * 4);
  float* qstar  = (float*)carve((size_t)B_ * 128 * 4);
  float* hs     = (float*)carve((size_t)B_ * 64 * 4);
  float* cs     = (float*)carve((size_t)B_ * 64 * 4);
  size_t zero_span = off;
  float* out_a  = (float*)carve((size_t)N_ * DIM_ * 4);
  float* out_b  = (float*)carve((size_t)N_ * DIM_ * 4);
  float* bt     = (float*)carve((size_t)N_ * DIM_ * 4);
  float* agg    = (float*)carve((size_t)N_ * DIM_ * 4);
  int*   estart = (int*)carve((size_t)(N_ + 1) * 4);
  int*   cursor = (int*)carve((size_t)N_ * 4);
  int*   epos   = (int*)carve((size_t)E_ * 4);
  int*   dst_s  = (int*)carve((size_t)E_ * 4);
  int*   gs     = (int*)carve((size_t)(B_ + 1) * 4);
  float* gihT   = (float*)carve((size_t)192 * 64 * 4);
  float* ghhT   = (float*)carve((size_t)192 * 64 * 4);
  float* lihT   = (float*)carve((size_t)256 * 128 * 4);
  float* lhhT   = (float*)carve((size_t)256 * 64 * 4);
  u16*   Ah     = (u16*)carve((size_t)NPAD * 64 * 2);
  u16*   Al     = (u16*)carve((size_t)NPAD * 64 * 2);
  u16*   BTh    = (u16*)carve((size_t)128 * 4096 * 2);
  u16*   BTl    = (u16*)carve((size_t)128 * 4096 * 2);
  float* he_s   = (float*)carve((size_t)E_ * H_ * 4);
  size_t common = off;
  // ---- h-chunk width: cap at 64 so V (164 MB) + he (51 MB) stay L3-resident ----
  int CW = 8;
  {
    const int cws[4] = {64, 32, 16, 8};
    for (int i = 0; i < 4; ++i) {
      size_t vb = (size_t)N_ * cws[i] * 64 * 4;
      if (common + vb <= ws_size) { CW = cws[i]; break; }
    }
  }
  float* V4 = (float*)carve((size_t)N_ * CW * 64 * 4);
  int nchunks = 128 / CW;
  int lcw = __builtin_ctz(CW);
  int H4Cb = CW / 4;

  // ---- init ----
  hipMemsetAsync(d_ws, 0, zero_span, stream);

  k_lin0<<<N_ / 4, 256, 0, stream>>>(x, lin0_w, lin0_b, out_a);
  k_hist<<<(E_ + 255) / 256, 256, 0, stream>>>(ei, outcnt, deg);
  k_scan<<<1, 1024, 0, stream>>>(outcnt, estart, cursor);
  k_scatter<<<(E_ + 255) / 256, 256, 0, stream>>>(ei, cursor, epos, dst_s);
  k_he<<<E_ / 32, 256, 0, stream>>>(ea, nn1_w, nn1_b, he_s, epos, lcw);
  k_gstart<<<(N_ + 255) / 256, 256, 0, stream>>>(batch, gs);
  k_transpose<<<128, 256, 0, stream>>>(gru_wih, gru_whh, lstm_wih, lstm_whh,
                                       gihT, ghhT, lihT, lhhT);
  k_prep_w<<<2048, 256, 0, stream>>>(nn2_w, BTh, BTl, CW);

  // ---- 2 conv+GRU steps ----
  float* cur = out_a;
  float* nxt = out_b;
  int egrid = (N_ + 3) / 4;
  int nblk = NPAD / 64;  // 157
  for (int t = 0; t < 2; ++t) {
    hipMemsetAsync(agg, 0, (size_t)N_ * DIM_ * 4, stream);
    k_bt<<<N_ / 4, 256, 0, stream>>>(cur, nn2_b, bt);
    k_split_a<<<(NPAD * 64 + 255) / 256, 256, 0, stream>>>(cur, Ah, Al);
    for (int chunk = 0; chunk < nchunks; ++chunk) {
      size_t boff = (size_t)chunk * CW * 4096;
      const float* heq = he_s + (size_t)chunk * E_ * CW;
      dim3 vg(nblk, H4Cb);
      k_vgemm_mfma<<<vg, 256, 0, stream>>>(Ah, Al, BTh + boff, BTl + boff, V4, H4Cb);
      int addbt = (chunk == 0) ? 1 : 0;
      switch (CW) {
        case 64:  k_edge<16><<<egrid, 256, 0, stream>>>(V4, heq, bt, dst_s, estart, agg, addbt); break;
        case 32:  k_edge<8><<<egrid, 256, 0, stream>>>(V4, heq, bt, dst_s, estart, agg, addbt); break;
        case 16:  k_edge<4><<<egrid, 256, 0, stream>>>(V4, heq, bt, dst_s, estart, agg, addbt); break;
        default:  k_edge<2><<<egrid, 256, 0, stream>>>(V4, heq, bt, dst_s, estart, agg, addbt); break;
      }
    }
    k_update<<<(N_ + 31) / 32, 256, 0, stream>>>(agg, deg, cur, root, cbias,
                                                 gihT, ghhT, gru_bih, gru_bhh, nxt);
    float* tmp = cur; cur = nxt; nxt = tmp;
  }

  // ---- Set2Set (2 fused steps; final MLP folded into step 2) ----
  k_s2s<<<B_, 256, 0, stream>>>(cur, gs, qstar, hs, cs, lihT, lhhT,
                                lstm_bih, lstm_bhh, lin1_w, lin1_b, lin2_w,
                                lin2_b, yout, 0);
  k_s2s<<<B_, 256, 0, stream>>>(cur, gs, qstar, hs, cs, lihT, lhhT,
                                lstm_bih, lstm_bhh, lin1_w, lin1_b, lin2_w,
                                lin2_b, yout, 1);
}